// Round 6
// baseline (456.637 us; speedup 1.0000x reference)
//
#include <hip/hip_runtime.h>
#include <cstdint>

typedef unsigned short u16;
typedef unsigned int   u32;
typedef unsigned long long u64;

#define G_ROWS 20000
#define G_PAD  20096      // 157 * 128 (conv padding; gemm over-reads past this, guarded on store)
#define T_DIM  1536
#define D_DIM  512
#define B_DIM  256
#define TOPK   32
#define SIM_SCALE 0.04419417382415922f   // 1/sqrt(512), screening only
#define SQRT_D    22.62741699796952f     // f32(math.sqrt(512)) — np divides by this
#define BOUND_EPS 2.0e-4f                // per-element screen-vs-np error bound (true ~5e-6; 40x margin)

typedef __bf16 bf16x8 __attribute__((ext_vector_type(8)));
typedef float  f32x4  __attribute__((ext_vector_type(4)));

__device__ __forceinline__ u16 f2bf(float f) {
  u32 u = __float_as_uint(f);
  u += 0x7fffu + ((u >> 16) & 1u);   // RNE
  return (u16)(u >> 16);
}
__device__ __forceinline__ float bf2f(u16 h) {
  return __uint_as_float(((u32)h) << 16);
}
__device__ __forceinline__ u32 fkey(float v) {   // order-preserving f32 -> u32
  u32 b = __float_as_uint(v);
  return (b & 0x80000000u) ? ~b : (b | 0x80000000u);
}
__device__ __forceinline__ float funkey(u32 o) {
  u32 b = (o & 0x80000000u) ? (o & 0x7FFFFFFFu) : ~o;
  return __uint_as_float(b);
}

// ---------------- fused preprocessing: convA | convB | transpose | mask-pack ----------------
// blocks [0,10048): conv tg_dec; [10048,10816): conv tf_base; [10816,11200): transpose tf_expr;
// [11200,14950): pack motif_mask (int32 0/1) -> bitmask (20000*48 u32 words)
__global__ __launch_bounds__(256) void prep(const float* __restrict__ tg_dec,
                                            const float* __restrict__ tf_base,
                                            const float* __restrict__ tf_expr,
                                            const int* __restrict__ mask,
                                            u16* __restrict__ Ah, u16* __restrict__ Al,
                                            u16* __restrict__ Bh, u16* __restrict__ Bl,
                                            float* __restrict__ tfT,
                                            u32* __restrict__ bits)
{
  __shared__ float tile[32][33];
  const int b = blockIdx.x;
  const int tid = threadIdx.x;
  if (b < 10816) {
    const float* src; u16 *hi, *lo; int valid_rows; int bb;
    if (b < 10048) { src = tg_dec; hi = Ah; lo = Al; valid_rows = G_ROWS; bb = b; }
    else           { src = tf_base; hi = Bh; lo = Bl; valid_rows = T_DIM; bb = b - 10048; }
    size_t i = ((size_t)bb * 256 + tid) * 4;
    int row = (int)(i >> 9);
    float4 a = make_float4(0.f, 0.f, 0.f, 0.f);
    if (row < valid_rows) a = *(const float4*)(src + i);
    float v[4] = {a.x, a.y, a.z, a.w};
    u16 h[4], l[4];
#pragma unroll
    for (int c = 0; c < 4; ++c) {
      h[c] = f2bf(v[c]);
      l[c] = f2bf(v[c] - bf2f(h[c]));
    }
    *(uint2*)(hi + i) = make_uint2((u32)h[0] | ((u32)h[1] << 16), (u32)h[2] | ((u32)h[3] << 16));
    *(uint2*)(lo + i) = make_uint2((u32)l[0] | ((u32)l[1] << 16), (u32)l[2] | ((u32)l[3] << 16));
  } else if (b < 11200) {
    const int t = b - 10816;
    const int x = tid & 31, y = tid >> 5;
    const int bt = (t % 48) * 32;
    const int bb = (t / 48) * 32;
#pragma unroll
    for (int i = 0; i < 32; i += 8) tile[y + i][x] = tf_expr[(size_t)(bb + y + i) * T_DIM + bt + x];
    __syncthreads();
#pragma unroll
    for (int i = 0; i < 32; i += 8) tfT[(size_t)(bt + y + i) * B_DIM + bb + x] = tile[x][y + i];
  } else {
    // mask pack: word w covers mask ints [32w, 32w+32); 960000 words total
    const int w = (b - 11200) * 256 + tid;     // < 960000 (3750 blocks * 256)
    const int* mp = mask + (size_t)w * 32;
    u32 bw = 0;
#pragma unroll
    for (int r = 0; r < 8; ++r) {
      int4 m = *(const int4*)(mp + r * 4);
      bw |= (m.x ? 1u : 0u) << (r * 4 + 0);
      bw |= (m.y ? 1u : 0u) << (r * 4 + 1);
      bw |= (m.z ? 1u : 0u) << (r * 4 + 2);
      bw |= (m.w ? 1u : 0u) << (r * 4 + 3);
    }
    bits[w] = bw;
  }
}

// ---------------- async global -> LDS, 16B/lane ----------------
__device__ __forceinline__ void gl16(const u16* g, u16* l) {
  __builtin_amdgcn_global_load_lds((__attribute__((address_space(1))) void*)(void*)g,
                                   (__attribute__((address_space(3))) void*)l, 16, 0, 0);
}

// ---------------- screening GEMM: C ~= (Ah+Al)(Bh+Bl)^T via 3 bf16 MFMA terms ----------------
// R3-proven structure: 256x256 tile, BK=32, 8 waves wave-tile 128x64, 4 half-buffers (128 KiB).
// 4 phases/K-tile, per-phase {ds_read | stage -> barrier -> lgkm0+sched_barrier -> MFMA -> barrier}.
// Stage decoupling: B(kt+1)@Ph1, A(kt+2)@Ph3; consume-wait vmcnt(4) (vmcnt(0) only at kt=15 —
// fixes latent under-wait: at kt=15 only A15,B15 in flight and vmcnt(4) left B15 unguaranteed).
#define NBX 6             // 1536 / 256
#define NWG 474           // 79 * 6

__global__ __launch_bounds__(512, 2) void gemm_split(const u16* __restrict__ Ah, const u16* __restrict__ Al,
                                                     const u16* __restrict__ Bh, const u16* __restrict__ Bl,
                                                     float* __restrict__ Sim)
{
  // u16 map: A-buf p at p*16384 (Ah 8192 | Al 8192); B-buf p at 32768 + p*16384 (Bh | Bl)
  __shared__ u16 sm[65536];   // 128 KiB

  // bijective XCD swizzle (m204; NWG % 8 == 2)
  const int orig = blockIdx.x;
  const int xcd  = orig & 7;
  const int q    = NWG >> 3, r = NWG & 7;
  const int wgid = (xcd < r ? xcd * (q + 1) : r * (q + 1) + (xcd - r) * q) + (orig >> 3);
  const int by   = wgid / NBX;
  const int bx   = wgid - by * NBX;
  const int bm0  = by * 256;
  const int bn0  = bx * 256;

  const int tid  = threadIdx.x;
  const int lane = tid & 63;
  const int wv   = tid >> 6;      // 0..7
  const int wm   = wv >> 2;       // 0..1 : wave row  (128-row strip)
  const int wn   = wv & 3;        // 0..3 : wave col  (64-col strip)
  const int la8  = lane << 3;     // u16 offset of this lane's 16B chunk in a subtile

  // staging roles: wave wv stages subtiles {2wv, 2wv+1}; subtile = 16 rows x 32 k,
  // 64 chunks of 16B in lane order (LDS dest linear: chunk l = lane l).
  const int sub  = wv << 1;
  const int srow = lane & 15;
  const int skc  = (lane >> 4) << 3;
  const u16* gA0  = Ah + (size_t)(bm0 + (sub + 0) * 16 + srow) * 512 + skc;
  const u16* gA1  = Ah + (size_t)(bm0 + (sub + 1) * 16 + srow) * 512 + skc;
  const u16* gAl0 = Al + (size_t)(bm0 + (sub + 0) * 16 + srow) * 512 + skc;
  const u16* gAl1 = Al + (size_t)(bm0 + (sub + 1) * 16 + srow) * 512 + skc;
  const u16* gB0  = Bh + (size_t)(bn0 + (sub + 0) * 16 + srow) * 512 + skc;
  const u16* gB1  = Bh + (size_t)(bn0 + (sub + 1) * 16 + srow) * 512 + skc;
  const u16* gBl0 = Bl + (size_t)(bn0 + (sub + 0) * 16 + srow) * 512 + skc;
  const u16* gBl1 = Bl + (size_t)(bn0 + (sub + 1) * 16 + srow) * 512 + skc;

#define STAGE_A(p, ktn) do {                                   \
    const size_t ko = (size_t)(ktn) << 5;                      \
    u16* d = sm + (p) * 16384 + sub * 512;                     \
    gl16(gA0 + ko,  d);                                        \
    gl16(gA1 + ko,  d + 512);                                  \
    gl16(gAl0 + ko, d + 8192);                                 \
    gl16(gAl1 + ko, d + 8192 + 512);                           \
  } while (0)
#define STAGE_B(p, ktn) do {                                   \
    const size_t ko = (size_t)(ktn) << 5;                      \
    u16* d = sm + 32768 + (p) * 16384 + sub * 512;             \
    gl16(gB0 + ko,  d);                                        \
    gl16(gB1 + ko,  d + 512);                                  \
    gl16(gBl0 + ko, d + 8192);                                 \
    gl16(gBl1 + ko, d + 8192 + 512);                           \
  } while (0)

  f32x4 acc[8][4];
#pragma unroll
  for (int i = 0; i < 8; ++i)
#pragma unroll
    for (int j = 0; j < 4; ++j) acc[i][j] = (f32x4){0.f, 0.f, 0.f, 0.f};

  bf16x8 aH[4], aL[4], bH[4], bL[4];

#define READ_A(rbA, half) do {                                                     \
    _Pragma("unroll")                                                              \
    for (int i = 0; i < 4; ++i) {                                                  \
      aH[i] = *(const bf16x8*)((rbA) + (wm * 8 + (half) * 4 + i) * 512 + la8);     \
      aL[i] = *(const bf16x8*)((rbA) + 8192 + (wm * 8 + (half) * 4 + i) * 512 + la8); \
    }                                                                              \
  } while (0)
#define READ_B(rbB, half) do {                                                     \
    _Pragma("unroll")                                                              \
    for (int i = 0; i < 2; ++i) {                                                  \
      bH[(half) * 2 + i] = *(const bf16x8*)((rbB) + (wn * 4 + (half) * 2 + i) * 512 + la8); \
      bL[(half) * 2 + i] = *(const bf16x8*)((rbB) + 8192 + (wn * 4 + (half) * 2 + i) * 512 + la8); \
    }                                                                              \
  } while (0)
#define MFMA_Q(qm, qn) do {                                                        \
    __builtin_amdgcn_s_setprio(1);                                                 \
    _Pragma("unroll")                                                              \
    for (int m2 = 0; m2 < 4; ++m2)                                                 \
      _Pragma("unroll")                                                            \
      for (int n2 = 0; n2 < 2; ++n2) {                                             \
        const int mi = (qm) * 4 + m2, ni = (qn) * 2 + n2;                          \
        acc[mi][ni] = __builtin_amdgcn_mfma_f32_16x16x32_bf16(aH[m2], bH[ni], acc[mi][ni], 0, 0, 0); \
        acc[mi][ni] = __builtin_amdgcn_mfma_f32_16x16x32_bf16(aH[m2], bL[ni], acc[mi][ni], 0, 0, 0); \
        acc[mi][ni] = __builtin_amdgcn_mfma_f32_16x16x32_bf16(aL[m2], bH[ni], acc[mi][ni], 0, 0, 0); \
      }                                                                            \
    __builtin_amdgcn_s_setprio(0);                                                 \
  } while (0)
#define LGKM0 do { asm volatile("s_waitcnt lgkmcnt(0)" ::: "memory"); __builtin_amdgcn_sched_barrier(0); } while (0)
#define BAR   do { __builtin_amdgcn_sched_barrier(0); __builtin_amdgcn_s_barrier(); } while (0)

  // prologue: A(0), B(0), A(1) in flight (12 loads/wave)
  STAGE_A(0, 0);
  STAGE_B(0, 0);
  STAGE_A(1, 1);

#pragma unroll 2
  for (int kt = 0; kt < 16; ++kt) {
    const u16* rbA = sm + (kt & 1) * 16384;
    const u16* rbB = sm + 32768 + (kt & 1) * 16384;

    // ---- Ph0: handshake (A(kt),B(kt) landed; A(kt+1) in flight); reads; MFMA Q00 ----
    if (kt < 15) asm volatile("s_waitcnt vmcnt(4)" ::: "memory");
    else         asm volatile("s_waitcnt vmcnt(0)" ::: "memory");
    BAR;
    READ_A(rbA, 0);
    READ_B(rbB, 0);
    LGKM0;
    MFMA_Q(0, 0);
    BAR;

    // ---- Ph1: stage B(kt+1) (buffer free since tile kt-1); read b-half 1; MFMA Q01 ----
    if (kt < 15) STAGE_B((kt + 1) & 1, kt + 1);
    READ_B(rbB, 1);
    LGKM0;
    MFMA_Q(0, 1);
    BAR;

    // ---- Ph2: read a-half 1; MFMA Q10 ----
    READ_A(rbA, 1);
    LGKM0;
    MFMA_Q(1, 0);
    BAR;                            // all waves' A-buf reads retired

    // ---- Ph3: stage A(kt+2) into A-buf[kt&1]; MFMA Q11 (pure register) ----
    if (kt < 14) STAGE_A(kt & 1, kt + 2);
    MFMA_Q(1, 1);
    // no barrier: Ph0(kt+1)'s vmcnt+barrier is the next sync point
  }
#undef STAGE_A
#undef STAGE_B
#undef READ_A
#undef READ_B
#undef MFMA_Q
#undef LGKM0
#undef BAR

  const int erow0 = bm0 + (wm << 7) + ((lane >> 4) << 2);
  const int ecol0 = bn0 + (wn << 6) + (lane & 15);
#pragma unroll
  for (int mi = 0; mi < 8; ++mi)
#pragma unroll
    for (int rr = 0; rr < 4; ++rr) {
      int row = erow0 + mi * 16 + rr;
      if (row < G_ROWS) {
#pragma unroll
        for (int ni = 0; ni < 4; ++ni)
          Sim[(size_t)row * T_DIM + ecol0 + ni * 16] = acc[mi][ni][rr] * SIM_SCALE;
      }
    }
}

// ---------------- helpers ----------------
__device__ __forceinline__ int count_ge(const float* v, float tau) {
  int c = 0;
#pragma unroll
  for (int j = 0; j < 24; ++j) c += (int)__popcll(__ballot(v[j] >= tau));
  return c;
}
// full 64-lane bitonic sort, descending by u64 key; returns this lane's sorted key
__device__ __forceinline__ u64 bitonic64_desc(u64 key, int lane) {
#pragma unroll
  for (int k = 2; k <= 64; k <<= 1) {
#pragma unroll
    for (int j = k >> 1; j > 0; j >>= 1) {
      u64 p = __shfl_xor(key, j, 64);
      bool lower = (lane & j) == 0;
      bool asc   = (lane & k) != 0;
      u64 mn = (key < p) ? key : p;
      u64 mx = (key < p) ? p : key;
      key = (lower == asc) ? mn : mx;
    }
  }
  return key;
}

// ---------------- per-row (1 wave/row): mask from packed bitmask (3.84 MB, L2-hot) ----------------
__global__ __launch_bounds__(256) void topk_kernel(float* __restrict__ Sim, const u32* __restrict__ bits,
                                                   const float* __restrict__ tg_dec,
                                                   const float* __restrict__ tf_base,
                                                   int* __restrict__ tIdx, float* __restrict__ tW)
{
  __shared__ u32 cval[4][64];
  __shared__ int cidxs[4][64];
  const int lane = threadIdx.x & 63;
  const int wv   = threadIdx.x >> 6;
  const int g    = blockIdx.x * 4 + wv;
  float* row = Sim + (size_t)g * T_DIM;
  const u32* brow = bits + (size_t)g * 48;

  // --- vectorized load of sim; mask via bit nibble: element e=256j+4*lane+c ->
  //     word 8j+(lane>>3), bits 4*(lane&7)+c ---
  float v[24];
#pragma unroll
  for (int j = 0; j < 6; ++j) {
    float4 q = *(const float4*)(row + j * 256 + lane * 4);
    u32 nib = brow[8 * j + (lane >> 3)] >> ((lane & 7) << 2);
    v[j * 4 + 0] = (nib & 1u) ? q.x : -INFINITY;
    v[j * 4 + 1] = (nib & 2u) ? q.y : -INFINITY;
    v[j * 4 + 2] = (nib & 4u) ? q.z : -INFINITY;
    v[j * 4 + 3] = (nib & 8u) ? q.w : -INFINITY;
  }

  // --- parallel 6-threshold ladder count (pure VALU) + valid count ---
  const float TH0 = 1.25f, TH1 = 1.40f, TH2 = 1.55f, TH3 = 1.70f, TH4 = 1.85f, TH5 = 2.00f;
  int n0 = 0, n1 = 0, n2 = 0, n3 = 0, n4 = 0, n5 = 0, nv = 0;
#pragma unroll
  for (int j = 0; j < 24; ++j) {
    float x = v[j];
    n0 += (x >= TH0); n1 += (x >= TH1); n2 += (x >= TH2);
    n3 += (x >= TH3); n4 += (x >= TH4); n5 += (x >= TH5);
    nv += (x != -INFINITY);
  }
  u64 p0 = (u64)(u32)n0 | ((u64)(u32)n1 << 16) | ((u64)(u32)n2 << 32) | ((u64)(u32)n3 << 48);
  u64 p1 = (u64)(u32)n4 | ((u64)(u32)n5 << 16) | ((u64)(u32)nv << 32);
#pragma unroll
  for (int off = 32; off > 0; off >>= 1) {
    p0 += __shfl_xor(p0, off, 64);
    p1 += __shfl_xor(p1, off, 64);
  }
  int c[6];
  c[0] = (int)(p0 & 0xFFFF); c[1] = (int)((p0 >> 16) & 0xFFFF);
  c[2] = (int)((p0 >> 32) & 0xFFFF); c[3] = (int)((p0 >> 48) & 0xFFFF);
  c[4] = (int)(p1 & 0xFFFF); c[5] = (int)((p1 >> 16) & 0xFFFF);
  const int cvalid = (int)((p1 >> 32) & 0xFFFF);

  // --- pick largest threshold with count >= 33; fallback bisect for gaps/extremes (~1%) ---
  float tau; int cnt;
  if (cvalid <= 64) { tau = -3.0e38f; cnt = cvalid; }
  else {
    int is = -1;
#pragma unroll
    for (int i = 0; i < 6; ++i) if (c[i] >= 33) is = i;
    const float THv[7] = {TH0, TH1, TH2, TH3, TH4, TH5, 8.0f};
    if (is >= 0 && c[is] <= 64) { tau = THv[is]; cnt = c[is]; }
    else {
      float lo, hi;
      if (is < 0) { lo = -4.0f; hi = TH0; }
      else        { lo = THv[is]; hi = THv[is + 1]; }
      tau = lo; cnt = 1000;
      for (int it = 0; it < 16; ++it) {
        float mid = 0.5f * (lo + hi);
        int cm = count_ge(v, mid);
        if (cm > 64)      lo = mid;
        else if (cm < 33) hi = mid;
        else { tau = mid; cnt = cm; break; }
      }
      if (cnt == 1000) tau = lo;
    }
  }

  // --- ballot-prefix compaction into wave-private LDS ---
  int base = 0;
#pragma unroll
  for (int j = 0; j < 24; ++j) {
    bool pred = (v[j] >= tau);
    u64 bmc = __ballot(pred);
    int pos = base + (int)__popcll(bmc & ((1ull << lane) - 1ull));
    int idx = (j >> 2) * 256 + lane * 4 + (j & 3);
    if (pred && pos < 64) { cval[wv][pos] = fkey(v[j]); cidxs[wv][pos] = idx; }
    base += (int)__popcll(bmc);
  }
  const int cnt_eff = (base < 64) ? base : 64;

  u64 key = 0;
  if (lane < cnt_eff)
    key = ((u64)cval[wv][lane] << 32) | (u64)(u32)(~(u32)cidxs[wv][lane]);

  key = bitonic64_desc(key, lane);
  int   myidx = (int)(~(u32)key);
  float myv   = (key != 0) ? funkey((u32)(key >> 32)) : -INFINITY;

  // --- np-replica ONLY if the 31/32 cut is truly contested ---
  float v31 = __shfl(myv, 31, 64);
  float v32 = __shfl(myv, 32, 64);
  if (cnt_eff > TOPK && (v31 - v32) < 2.0f * BOUND_EPS) {
    bool flag = (lane < cnt_eff) &&
                (myv >= v32 - 2.0f * BOUND_EPS) && (myv <= v31 + 2.0f * BOUND_EPS);
    if (flag) {
      // bit-exact np replica: OpenBLAS sgemm sequential-K FMA chain, kc split 384|128
      const float* arow_g = tg_dec + (size_t)g * D_DIM;
      const float* brow2  = tf_base + (size_t)myidx * D_DIM;
      float s1 = 0.f, s2 = 0.f;
#pragma unroll 8
      for (int k = 0; k < 384; k += 4) {
        float4 av = *(const float4*)(arow_g + k);
        float4 bv = *(const float4*)(brow2 + k);
        s1 = fmaf(av.x, bv.x, s1); s1 = fmaf(av.y, bv.y, s1);
        s1 = fmaf(av.z, bv.z, s1); s1 = fmaf(av.w, bv.w, s1);
      }
#pragma unroll 8
      for (int k = 384; k < 512; k += 4) {
        float4 av = *(const float4*)(arow_g + k);
        float4 bv = *(const float4*)(brow2 + k);
        s2 = fmaf(av.x, bv.x, s2); s2 = fmaf(av.y, bv.y, s2);
        s2 = fmaf(av.z, bv.z, s2); s2 = fmaf(av.w, bv.w, s2);
      }
      myv = (s1 + s2) / SQRT_D;
      key = ((u64)fkey(myv) << 32) | (u64)(u32)(~(u32)myidx);
    }
    key = bitonic64_desc(key, lane);
    myidx = (int)(~(u32)key);
    myv   = (key != 0) ? funkey((u32)(key >> 32)) : -INFINITY;
  }

  // --- weights from sorted lanes 0..31 ---
  const bool selme = (lane < TOPK) && (lane < cnt_eff);
  float mx = __shfl(myv, 0, 64);
  float e = selme ? __expf(myv - mx) : 0.f;
  float E = e;
#pragma unroll
  for (int off = 32; off > 0; off >>= 1) E += __shfl_xor(E, off, 64);
  float rden = (E > 0.f) ? (1.f / E) : 0.f;
  float w = e * rden;

  // --- dense zero write (nontemporal: never re-read), drain, then sparse scatter ---
  const f32x4 z4 = (f32x4){0.f, 0.f, 0.f, 0.f};
#pragma unroll
  for (int j = 0; j < 6; ++j)
    __builtin_nontemporal_store(z4, (f32x4*)(row + j * 256 + lane * 4));
  asm volatile("s_waitcnt vmcnt(0)" ::: "memory");   // zeros visible before scatter
  if (selme) row[myidx] = w;

  if (cnt_eff < TOPK && lane >= cnt_eff && lane < TOPK) {
    tIdx[(size_t)g * TOPK + lane] = 0; tW[(size_t)g * TOPK + lane] = 0.f;
  }
  if (selme) {
    tIdx[(size_t)g * TOPK + lane] = myidx;
    tW[(size_t)g * TOPK + lane]   = w;
  }
}

// ---------------- out0[b,g] = scale * sum_k w[g,k] * tfT[idx[g,k], b] ----------------
// per-wave: 4 g-rows; per-thread: 4 b-values via float4 gathers (wave load = full 1KB row)
__global__ __launch_bounds__(256) void combine_kernel(const float* __restrict__ tfT, const int* __restrict__ tIdx,
                                                      const float* __restrict__ tW, const float* __restrict__ scalep,
                                                      float* __restrict__ out0)
{
  __shared__ int   sIdx[16 * 32];
  __shared__ float sW[16 * 32];
  const int tid  = threadIdx.x;
  const int lane = tid & 63;
  const int wv   = tid >> 6;
  const int g0   = blockIdx.x * 16;
  for (int i = tid; i < 512; i += 256) {
    sIdx[i] = tIdx[(size_t)g0 * 32 + i];
    sW[i]   = tW[(size_t)g0 * 32 + i];
  }
  __syncthreads();
  const float scale = scalep[0];
  const int gl = wv << 2;                      // this wave's 4 local g-rows
  float acc[4][4];
#pragma unroll
  for (int gi = 0; gi < 4; ++gi)
#pragma unroll
    for (int c = 0; c < 4; ++c) acc[gi][c] = 0.f;

#pragma unroll 4
  for (int k = 0; k < 32; ++k) {
#pragma unroll
    for (int gi = 0; gi < 4; ++gi) {
      int   t = sIdx[(gl + gi) * 32 + k];
      float w = sW[(gl + gi) * 32 + k];
      float4 vv = *(const float4*)(tfT + (size_t)t * B_DIM + lane * 4);
      acc[gi][0] = fmaf(w, vv.x, acc[gi][0]);
      acc[gi][1] = fmaf(w, vv.y, acc[gi][1]);
      acc[gi][2] = fmaf(w, vv.z, acc[gi][2]);
      acc[gi][3] = fmaf(w, vv.w, acc[gi][3]);
    }
  }
  // write: for each of this thread's 4 b-values, float4 across its wave's 4 consecutive g
#pragma unroll
  for (int c = 0; c < 4; ++c) {
    f32x4 o = (f32x4){scale * acc[0][c], scale * acc[1][c], scale * acc[2][c], scale * acc[3][c]};
    __builtin_nontemporal_store(o, (f32x4*)(out0 + (size_t)(lane * 4 + c) * G_ROWS + g0 + gl));
  }
}

extern "C" void kernel_launch(void* const* d_in, const int* in_sizes, int n_in,
                              void* d_out, int out_size, void* d_ws, size_t ws_size,
                              hipStream_t stream)
{
  const float* tg_dec     = (const float*)d_in[0];
  const float* tf_base    = (const float*)d_in[1];
  const float* tf_expr    = (const float*)d_in[2];
  const int*   motif_mask = (const int*)d_in[3];
  const float* scale      = (const float*)d_in[4];

  float* out0 = (float*)d_out;                           // [B, G]
  float* attn = out0 + (size_t)B_DIM * G_ROWS;           // [G, T] — Sim scratch, overwritten in place
  // bitmask (20000*48 u32 = 3.84 MB) lives in the out0 region: written by prep, read by topk,
  // overwritten by combine at the very end. gemm writes only the attn region (disjoint).
  u32* bits = (u32*)d_out;

  char* ws = (char*)d_ws;
  u16*   Ah    = (u16*)(ws);                             // G_PAD*512 bf16
  u16*   Al    = (u16*)(ws + 20578304);
  u16*   Bh    = (u16*)(ws + 41156608);                  // 1536*512 bf16
  u16*   Bl    = (u16*)(ws + 42729472);
  float* tfT   = (float*)(ws + 44302336);                // [T, B] f32
  int*   tIdx  = (int*)(ws + 45875200);                  // [G, 32]
  float* tW    = (float*)(ws + 48435200);                // [G, 32]

  prep<<<14950, 256, 0, stream>>>(tg_dec, tf_base, tf_expr, motif_mask, Ah, Al, Bh, Bl, tfT, bits);
  gemm_split<<<NWG, 512, 0, stream>>>(Ah, Al, Bh, Bl, attn);
  topk_kernel<<<5000, 256, 0, stream>>>(attn, bits, tg_dec, tf_base, tIdx, tW);
  combine_kernel<<<1250, 256, 0, stream>>>(tfT, tIdx, tW, scale, out0);
}

// Round 7
// 430.472 us; speedup vs baseline: 1.0608x; 1.0608x over previous
//
#include <hip/hip_runtime.h>
#include <cstdint>

typedef unsigned short u16;
typedef unsigned int   u32;
typedef unsigned long long u64;

#define G_ROWS 20000
#define G_PAD  20096      // 157 * 128 (conv padding; gemm over-reads past this, guarded on store)
#define T_DIM  1536
#define D_DIM  512
#define B_DIM  256
#define TOPK   32
#define SIM_SCALE 0.04419417382415922f   // 1/sqrt(512), screening only
#define SQRT_D    22.62741699796952f     // f32(math.sqrt(512)) — np divides by this
#define BOUND_EPS 2.0e-4f                // per-element screen-vs-np error bound (true ~5e-6; 40x margin)

typedef __bf16 bf16x8 __attribute__((ext_vector_type(8)));
typedef float  f32x4  __attribute__((ext_vector_type(4)));

__device__ __forceinline__ u16 f2bf(float f) {
  u32 u = __float_as_uint(f);
  u += 0x7fffu + ((u >> 16) & 1u);   // RNE
  return (u16)(u >> 16);
}
__device__ __forceinline__ float bf2f(u16 h) {
  return __uint_as_float(((u32)h) << 16);
}
__device__ __forceinline__ u32 fkey(float v) {   // order-preserving f32 -> u32
  u32 b = __float_as_uint(v);
  return (b & 0x80000000u) ? ~b : (b | 0x80000000u);
}
__device__ __forceinline__ float funkey(u32 o) {
  u32 b = (o & 0x80000000u) ? (o & 0x7FFFFFFFu) : ~o;
  return __uint_as_float(b);
}

// ---------------- fused preprocessing: convA | convB | transpose ----------------
__global__ __launch_bounds__(256) void prep(const float* __restrict__ tg_dec,
                                            const float* __restrict__ tf_base,
                                            const float* __restrict__ tf_expr,
                                            u16* __restrict__ Ah, u16* __restrict__ Al,
                                            u16* __restrict__ Bh, u16* __restrict__ Bl,
                                            float* __restrict__ tfT)
{
  __shared__ float tile[32][33];
  const int b = blockIdx.x;
  const int tid = threadIdx.x;
  if (b < 10816) {
    const float* src; u16 *hi, *lo; int valid_rows; int bb;
    if (b < 10048) { src = tg_dec; hi = Ah; lo = Al; valid_rows = G_ROWS; bb = b; }
    else           { src = tf_base; hi = Bh; lo = Bl; valid_rows = T_DIM; bb = b - 10048; }
    size_t i = ((size_t)bb * 256 + tid) * 4;
    int row = (int)(i >> 9);
    float4 a = make_float4(0.f, 0.f, 0.f, 0.f);
    if (row < valid_rows) a = *(const float4*)(src + i);
    float v[4] = {a.x, a.y, a.z, a.w};
    u16 h[4], l[4];
#pragma unroll
    for (int c = 0; c < 4; ++c) {
      h[c] = f2bf(v[c]);
      l[c] = f2bf(v[c] - bf2f(h[c]));
    }
    *(uint2*)(hi + i) = make_uint2((u32)h[0] | ((u32)h[1] << 16), (u32)h[2] | ((u32)h[3] << 16));
    *(uint2*)(lo + i) = make_uint2((u32)l[0] | ((u32)l[1] << 16), (u32)l[2] | ((u32)l[3] << 16));
  } else {
    const int t = b - 10816;
    const int x = tid & 31, y = tid >> 5;
    const int bt = (t % 48) * 32;
    const int bb = (t / 48) * 32;
#pragma unroll
    for (int i = 0; i < 32; i += 8) tile[y + i][x] = tf_expr[(size_t)(bb + y + i) * T_DIM + bt + x];
    __syncthreads();
#pragma unroll
    for (int i = 0; i < 32; i += 8) tfT[(size_t)(bt + y + i) * B_DIM + bb + x] = tile[x][y + i];
  }
}

// ---------------- async global -> LDS, 16B/lane ----------------
__device__ __forceinline__ void gl16(const u16* g, u16* l) {
  __builtin_amdgcn_global_load_lds((__attribute__((address_space(1))) void*)(void*)g,
                                   (__attribute__((address_space(3))) void*)l, 16, 0, 0);
}

// ---------------- screening GEMM: C ~= (Ah+Al)(Bh+Bl)^T via 3 bf16 MFMA terms ----------------
// R6-proven (102 us, MfmaUtil 40%): 256x256 tile, BK=32, 8 waves wave-tile 128x64,
// 4 half-buffers (128 KiB). 4 phases/K-tile; stage decoupling B(kt+1)@Ph1, A(kt+2)@Ph3;
// consume-wait vmcnt(4), vmcnt(0) only at kt=15.
#define NBX 6             // 1536 / 256
#define NWG 474           // 79 * 6

__global__ __launch_bounds__(512, 2) void gemm_split(const u16* __restrict__ Ah, const u16* __restrict__ Al,
                                                     const u16* __restrict__ Bh, const u16* __restrict__ Bl,
                                                     float* __restrict__ Sim)
{
  // u16 map: A-buf p at p*16384 (Ah 8192 | Al 8192); B-buf p at 32768 + p*16384 (Bh | Bl)
  __shared__ u16 sm[65536];   // 128 KiB

  // bijective XCD swizzle (m204; NWG % 8 == 2)
  const int orig = blockIdx.x;
  const int xcd  = orig & 7;
  const int q    = NWG >> 3, r = NWG & 7;
  const int wgid = (xcd < r ? xcd * (q + 1) : r * (q + 1) + (xcd - r) * q) + (orig >> 3);
  const int by   = wgid / NBX;
  const int bx   = wgid - by * NBX;
  const int bm0  = by * 256;
  const int bn0  = bx * 256;

  const int tid  = threadIdx.x;
  const int lane = tid & 63;
  const int wv   = tid >> 6;      // 0..7
  const int wm   = wv >> 2;       // 0..1 : wave row  (128-row strip)
  const int wn   = wv & 3;        // 0..3 : wave col  (64-col strip)
  const int la8  = lane << 3;     // u16 offset of this lane's 16B chunk in a subtile

  // staging roles: wave wv stages subtiles {2wv, 2wv+1}; subtile = 16 rows x 32 k,
  // 64 chunks of 16B in lane order (LDS dest linear: chunk l = lane l).
  const int sub  = wv << 1;
  const int srow = lane & 15;
  const int skc  = (lane >> 4) << 3;
  const u16* gA0  = Ah + (size_t)(bm0 + (sub + 0) * 16 + srow) * 512 + skc;
  const u16* gA1  = Ah + (size_t)(bm0 + (sub + 1) * 16 + srow) * 512 + skc;
  const u16* gAl0 = Al + (size_t)(bm0 + (sub + 0) * 16 + srow) * 512 + skc;
  const u16* gAl1 = Al + (size_t)(bm0 + (sub + 1) * 16 + srow) * 512 + skc;
  const u16* gB0  = Bh + (size_t)(bn0 + (sub + 0) * 16 + srow) * 512 + skc;
  const u16* gB1  = Bh + (size_t)(bn0 + (sub + 1) * 16 + srow) * 512 + skc;
  const u16* gBl0 = Bl + (size_t)(bn0 + (sub + 0) * 16 + srow) * 512 + skc;
  const u16* gBl1 = Bl + (size_t)(bn0 + (sub + 1) * 16 + srow) * 512 + skc;

#define STAGE_A(p, ktn) do {                                   \
    const size_t ko = (size_t)(ktn) << 5;                      \
    u16* d = sm + (p) * 16384 + sub * 512;                     \
    gl16(gA0 + ko,  d);                                        \
    gl16(gA1 + ko,  d + 512);                                  \
    gl16(gAl0 + ko, d + 8192);                                 \
    gl16(gAl1 + ko, d + 8192 + 512);                           \
  } while (0)
#define STAGE_B(p, ktn) do {                                   \
    const size_t ko = (size_t)(ktn) << 5;                      \
    u16* d = sm + 32768 + (p) * 16384 + sub * 512;             \
    gl16(gB0 + ko,  d);                                        \
    gl16(gB1 + ko,  d + 512);                                  \
    gl16(gBl0 + ko, d + 8192);                                 \
    gl16(gBl1 + ko, d + 8192 + 512);                           \
  } while (0)

  f32x4 acc[8][4];
#pragma unroll
  for (int i = 0; i < 8; ++i)
#pragma unroll
    for (int j = 0; j < 4; ++j) acc[i][j] = (f32x4){0.f, 0.f, 0.f, 0.f};

  bf16x8 aH[4], aL[4], bH[4], bL[4];

#define READ_A(rbA, half) do {                                                     \
    _Pragma("unroll")                                                              \
    for (int i = 0; i < 4; ++i) {                                                  \
      aH[i] = *(const bf16x8*)((rbA) + (wm * 8 + (half) * 4 + i) * 512 + la8);     \
      aL[i] = *(const bf16x8*)((rbA) + 8192 + (wm * 8 + (half) * 4 + i) * 512 + la8); \
    }                                                                              \
  } while (0)
#define READ_B(rbB, half) do {                                                     \
    _Pragma("unroll")                                                              \
    for (int i = 0; i < 2; ++i) {                                                  \
      bH[(half) * 2 + i] = *(const bf16x8*)((rbB) + (wn * 4 + (half) * 2 + i) * 512 + la8); \
      bL[(half) * 2 + i] = *(const bf16x8*)((rbB) + 8192 + (wn * 4 + (half) * 2 + i) * 512 + la8); \
    }                                                                              \
  } while (0)
#define MFMA_Q(qm, qn) do {                                                        \
    __builtin_amdgcn_s_setprio(1);                                                 \
    _Pragma("unroll")                                                              \
    for (int m2 = 0; m2 < 4; ++m2)                                                 \
      _Pragma("unroll")                                                            \
      for (int n2 = 0; n2 < 2; ++n2) {                                             \
        const int mi = (qm) * 4 + m2, ni = (qn) * 2 + n2;                          \
        acc[mi][ni] = __builtin_amdgcn_mfma_f32_16x16x32_bf16(aH[m2], bH[ni], acc[mi][ni], 0, 0, 0); \
        acc[mi][ni] = __builtin_amdgcn_mfma_f32_16x16x32_bf16(aH[m2], bL[ni], acc[mi][ni], 0, 0, 0); \
        acc[mi][ni] = __builtin_amdgcn_mfma_f32_16x16x32_bf16(aL[m2], bH[ni], acc[mi][ni], 0, 0, 0); \
      }                                                                            \
    __builtin_amdgcn_s_setprio(0);                                                 \
  } while (0)
#define LGKM0 do { asm volatile("s_waitcnt lgkmcnt(0)" ::: "memory"); __builtin_amdgcn_sched_barrier(0); } while (0)
#define BAR   do { __builtin_amdgcn_sched_barrier(0); __builtin_amdgcn_s_barrier(); } while (0)

  // prologue: A(0), B(0), A(1) in flight (12 loads/wave)
  STAGE_A(0, 0);
  STAGE_B(0, 0);
  STAGE_A(1, 1);

#pragma unroll 2
  for (int kt = 0; kt < 16; ++kt) {
    const u16* rbA = sm + (kt & 1) * 16384;
    const u16* rbB = sm + 32768 + (kt & 1) * 16384;

    // ---- Ph0: handshake (A(kt),B(kt) landed; A(kt+1) in flight); reads; MFMA Q00 ----
    if (kt < 15) asm volatile("s_waitcnt vmcnt(4)" ::: "memory");
    else         asm volatile("s_waitcnt vmcnt(0)" ::: "memory");
    BAR;
    READ_A(rbA, 0);
    READ_B(rbB, 0);
    LGKM0;
    MFMA_Q(0, 0);
    BAR;

    // ---- Ph1: stage B(kt+1) (buffer free since tile kt-1); read b-half 1; MFMA Q01 ----
    if (kt < 15) STAGE_B((kt + 1) & 1, kt + 1);
    READ_B(rbB, 1);
    LGKM0;
    MFMA_Q(0, 1);
    BAR;

    // ---- Ph2: read a-half 1; MFMA Q10 ----
    READ_A(rbA, 1);
    LGKM0;
    MFMA_Q(1, 0);
    BAR;                            // all waves' A-buf reads retired

    // ---- Ph3: stage A(kt+2) into A-buf[kt&1]; MFMA Q11 (pure register) ----
    if (kt < 14) STAGE_A(kt & 1, kt + 2);
    MFMA_Q(1, 1);
    // no barrier: Ph0(kt+1)'s vmcnt+barrier is the next sync point
  }
#undef STAGE_A
#undef STAGE_B
#undef READ_A
#undef READ_B
#undef MFMA_Q
#undef LGKM0
#undef BAR

  const int erow0 = bm0 + (wm << 7) + ((lane >> 4) << 2);
  const int ecol0 = bn0 + (wn << 6) + (lane & 15);
#pragma unroll
  for (int mi = 0; mi < 8; ++mi)
#pragma unroll
    for (int rr = 0; rr < 4; ++rr) {
      int row = erow0 + mi * 16 + rr;
      if (row < G_ROWS) {
#pragma unroll
        for (int ni = 0; ni < 4; ++ni)
          Sim[(size_t)row * T_DIM + ecol0 + ni * 16] = acc[mi][ni][rr] * SIM_SCALE;
      }
    }
}

// ---------------- helpers ----------------
__device__ __forceinline__ int count_ge(const float* v, float tau) {
  int c = 0;
#pragma unroll
  for (int j = 0; j < 24; ++j) c += (int)__popcll(__ballot(v[j] >= tau));
  return c;
}
// full 64-lane bitonic sort, descending by u64 key; returns this lane's sorted key
__device__ __forceinline__ u64 bitonic64_desc(u64 key, int lane) {
#pragma unroll
  for (int k = 2; k <= 64; k <<= 1) {
#pragma unroll
    for (int j = k >> 1; j > 0; j >>= 1) {
      u64 p = __shfl_xor(key, j, 64);
      bool lower = (lane & j) == 0;
      bool asc   = (lane & k) != 0;
      u64 mn = (key < p) ? key : p;
      u64 mx = (key < p) ? p : key;
      key = (lower == asc) ? mn : mx;
    }
  }
  return key;
}

// ---------------- fused top-k + combine (1 wave/row) ----------------
// topk selects/normalizes as before; then the wave directly computes
// out0[b, g] = scale * sum_k w_k * tfT[idx_k, b] (idx/w broadcast via shfl from sorted lanes),
// staged through a 4KB LDS transpose so out0 writes stay 16B-chunk/L2-write-combined.
__global__ __launch_bounds__(256) void topk_combine(float* __restrict__ Sim, const int* __restrict__ mask,
                                                    const float* __restrict__ tg_dec,
                                                    const float* __restrict__ tf_base,
                                                    const float* __restrict__ tfT,
                                                    const float* __restrict__ scalep,
                                                    float* __restrict__ out0)
{
  __shared__ u32 cval[4][64];
  __shared__ int cidxs[4][64];
  __shared__ float sOut[4][256];
  const int lane = threadIdx.x & 63;
  const int wv   = threadIdx.x >> 6;
  const int g    = blockIdx.x * 4 + wv;
  float* row = Sim + (size_t)g * T_DIM;
  const int* mrow = mask + (size_t)g * T_DIM;

  // --- vectorized load of sim + mask; apply mask -> -inf ---
  float v[24];
#pragma unroll
  for (int j = 0; j < 6; ++j) {
    float4 q = *(const float4*)(row + j * 256 + lane * 4);
    int4  mq = *(const int4*)(mrow + j * 256 + lane * 4);
    v[j * 4 + 0] = mq.x ? q.x : -INFINITY;
    v[j * 4 + 1] = mq.y ? q.y : -INFINITY;
    v[j * 4 + 2] = mq.z ? q.z : -INFINITY;
    v[j * 4 + 3] = mq.w ? q.w : -INFINITY;
  }

  // --- parallel 6-threshold ladder count (pure VALU) + valid count ---
  const float TH0 = 1.25f, TH1 = 1.40f, TH2 = 1.55f, TH3 = 1.70f, TH4 = 1.85f, TH5 = 2.00f;
  int n0 = 0, n1 = 0, n2 = 0, n3 = 0, n4 = 0, n5 = 0, nv = 0;
#pragma unroll
  for (int j = 0; j < 24; ++j) {
    float x = v[j];
    n0 += (x >= TH0); n1 += (x >= TH1); n2 += (x >= TH2);
    n3 += (x >= TH3); n4 += (x >= TH4); n5 += (x >= TH5);
    nv += (x != -INFINITY);
  }
  u64 p0 = (u64)(u32)n0 | ((u64)(u32)n1 << 16) | ((u64)(u32)n2 << 32) | ((u64)(u32)n3 << 48);
  u64 p1 = (u64)(u32)n4 | ((u64)(u32)n5 << 16) | ((u64)(u32)nv << 32);
#pragma unroll
  for (int off = 32; off > 0; off >>= 1) {
    p0 += __shfl_xor(p0, off, 64);
    p1 += __shfl_xor(p1, off, 64);
  }
  int c[6];
  c[0] = (int)(p0 & 0xFFFF); c[1] = (int)((p0 >> 16) & 0xFFFF);
  c[2] = (int)((p0 >> 32) & 0xFFFF); c[3] = (int)((p0 >> 48) & 0xFFFF);
  c[4] = (int)(p1 & 0xFFFF); c[5] = (int)((p1 >> 16) & 0xFFFF);
  const int cvalid = (int)((p1 >> 32) & 0xFFFF);

  // --- pick largest threshold with count >= 33; fallback bisect for gaps/extremes (~1%) ---
  float tau; int cnt;
  if (cvalid <= 64) { tau = -3.0e38f; cnt = cvalid; }
  else {
    int is = -1;
#pragma unroll
    for (int i = 0; i < 6; ++i) if (c[i] >= 33) is = i;
    const float THv[7] = {TH0, TH1, TH2, TH3, TH4, TH5, 8.0f};
    if (is >= 0 && c[is] <= 64) { tau = THv[is]; cnt = c[is]; }
    else {
      float lo, hi;
      if (is < 0) { lo = -4.0f; hi = TH0; }
      else        { lo = THv[is]; hi = THv[is + 1]; }
      tau = lo; cnt = 1000;
      for (int it = 0; it < 16; ++it) {
        float mid = 0.5f * (lo + hi);
        int cm = count_ge(v, mid);
        if (cm > 64)      lo = mid;
        else if (cm < 33) hi = mid;
        else { tau = mid; cnt = cm; break; }
      }
      if (cnt == 1000) tau = lo;
    }
  }

  // --- ballot-prefix compaction into wave-private LDS ---
  int base = 0;
#pragma unroll
  for (int j = 0; j < 24; ++j) {
    bool pred = (v[j] >= tau);
    u64 bmc = __ballot(pred);
    int pos = base + (int)__popcll(bmc & ((1ull << lane) - 1ull));
    int idx = (j >> 2) * 256 + lane * 4 + (j & 3);
    if (pred && pos < 64) { cval[wv][pos] = fkey(v[j]); cidxs[wv][pos] = idx; }
    base += (int)__popcll(bmc);
  }
  const int cnt_eff = (base < 64) ? base : 64;

  u64 key = 0;
  if (lane < cnt_eff)
    key = ((u64)cval[wv][lane] << 32) | (u64)(u32)(~(u32)cidxs[wv][lane]);

  key = bitonic64_desc(key, lane);
  int   myidx = (int)(~(u32)key);
  float myv   = (key != 0) ? funkey((u32)(key >> 32)) : -INFINITY;

  // --- np-replica ONLY if the 31/32 cut is truly contested ---
  float v31 = __shfl(myv, 31, 64);
  float v32 = __shfl(myv, 32, 64);
  if (cnt_eff > TOPK && (v31 - v32) < 2.0f * BOUND_EPS) {
    bool flag = (lane < cnt_eff) &&
                (myv >= v32 - 2.0f * BOUND_EPS) && (myv <= v31 + 2.0f * BOUND_EPS);
    if (flag) {
      // bit-exact np replica: OpenBLAS sgemm sequential-K FMA chain, kc split 384|128
      const float* arow_g = tg_dec + (size_t)g * D_DIM;
      const float* brow2  = tf_base + (size_t)myidx * D_DIM;
      float s1 = 0.f, s2 = 0.f;
#pragma unroll 8
      for (int k = 0; k < 384; k += 4) {
        float4 av = *(const float4*)(arow_g + k);
        float4 bv = *(const float4*)(brow2 + k);
        s1 = fmaf(av.x, bv.x, s1); s1 = fmaf(av.y, bv.y, s1);
        s1 = fmaf(av.z, bv.z, s1); s1 = fmaf(av.w, bv.w, s1);
      }
#pragma unroll 8
      for (int k = 384; k < 512; k += 4) {
        float4 av = *(const float4*)(arow_g + k);
        float4 bv = *(const float4*)(brow2 + k);
        s2 = fmaf(av.x, bv.x, s2); s2 = fmaf(av.y, bv.y, s2);
        s2 = fmaf(av.z, bv.z, s2); s2 = fmaf(av.w, bv.w, s2);
      }
      myv = (s1 + s2) / SQRT_D;
      key = ((u64)fkey(myv) << 32) | (u64)(u32)(~(u32)myidx);
    }
    key = bitonic64_desc(key, lane);
    myidx = (int)(~(u32)key);
    myv   = (key != 0) ? funkey((u32)(key >> 32)) : -INFINITY;
  }

  // --- weights from sorted lanes 0..31 ---
  const bool selme = (lane < TOPK) && (lane < cnt_eff);
  float mx = __shfl(myv, 0, 64);
  float e = selme ? __expf(myv - mx) : 0.f;
  float E = e;
#pragma unroll
  for (int off = 32; off > 0; off >>= 1) E += __shfl_xor(E, off, 64);
  float rden = (E > 0.f) ? (1.f / E) : 0.f;
  float w = e * rden;

  // --- dense zero write (issues early; drains before scatter below) ---
  const float4 z4 = make_float4(0.f, 0.f, 0.f, 0.f);
#pragma unroll
  for (int j = 0; j < 6; ++j) *(float4*)(row + j * 256 + lane * 4) = z4;

  // --- fused combine: acc[c] = sum_k w_k * tfT[idx_k, lane*4+c] (tfT is 1.5 MB, L2-hot) ---
  float a0 = 0.f, a1 = 0.f, a2 = 0.f, a3 = 0.f;
#pragma unroll 4
  for (int k = 0; k < TOPK; ++k) {
    float wk = __shfl(w, k, 64);       // wave-uniform after shfl
    int   ik = __shfl(myidx, k, 64);
    if (wk > 0.f) {                    // uniform branch; guards garbage idx when k >= cnt_eff
      float4 vv = *(const float4*)(tfT + (size_t)ik * B_DIM + lane * 4);
      a0 = fmaf(wk, vv.x, a0); a1 = fmaf(wk, vv.y, a1);
      a2 = fmaf(wk, vv.z, a2); a3 = fmaf(wk, vv.w, a3);
    }
  }
  const float scale = scalep[0];
  // LDS transpose: sOut[wv][b] so the out0 write is float4 per thread (16B chunks, L2-combined)
  *(float4*)(&sOut[wv][lane * 4]) = make_float4(scale * a0, scale * a1, scale * a2, scale * a3);
  __syncthreads();
  {
    const int t = threadIdx.x;         // b index
    const int g0 = blockIdx.x * 4;
    float4 o = make_float4(sOut[0][t], sOut[1][t], sOut[2][t], sOut[3][t]);
    *(float4*)(out0 + (size_t)t * G_ROWS + g0) = o;
  }

  // --- drain zeros, then sparse scatter of the 32 weights ---
  asm volatile("s_waitcnt vmcnt(0)" ::: "memory");
  if (selme) row[myidx] = w;
}

extern "C" void kernel_launch(void* const* d_in, const int* in_sizes, int n_in,
                              void* d_out, int out_size, void* d_ws, size_t ws_size,
                              hipStream_t stream)
{
  const float* tg_dec     = (const float*)d_in[0];
  const float* tf_base    = (const float*)d_in[1];
  const float* tf_expr    = (const float*)d_in[2];
  const int*   motif_mask = (const int*)d_in[3];
  const float* scale      = (const float*)d_in[4];

  float* out0 = (float*)d_out;                           // [B, G]
  float* attn = out0 + (size_t)B_DIM * G_ROWS;           // [G, T] — Sim scratch, overwritten in place

  char* ws = (char*)d_ws;
  u16*   Ah    = (u16*)(ws);                             // G_PAD*512 bf16
  u16*   Al    = (u16*)(ws + 20578304);
  u16*   Bh    = (u16*)(ws + 41156608);                  // 1536*512 bf16
  u16*   Bl    = (u16*)(ws + 42729472);
  float* tfT   = (float*)(ws + 44302336);                // [T, B] f32

  prep<<<11200, 256, 0, stream>>>(tg_dec, tf_base, tf_expr, Ah, Al, Bh, Bl, tfT);
  gemm_split<<<NWG, 512, 0, stream>>>(Ah, Al, Bh, Bl, attn);
  topk_combine<<<5000, 256, 0, stream>>>(attn, motif_mask, tg_dec, tf_base, tfT, scale, out0);
}

// Round 8
// 421.678 us; speedup vs baseline: 1.0829x; 1.0209x over previous
//
#include <hip/hip_runtime.h>
#include <cstdint>

typedef unsigned short u16;
typedef unsigned int   u32;
typedef unsigned long long u64;

#define G_ROWS 20000
#define G_PAD  20096      // 157 * 128 (conv padding; gemm over-reads past this, guarded on store)
#define T_DIM  1536
#define D_DIM  512
#define B_DIM  256
#define TOPK   32
#define SIM_SCALE 0.04419417382415922f   // 1/sqrt(512), screening only
#define SQRT_D    22.62741699796952f     // f32(math.sqrt(512)) — np divides by this
#define BOUND_EPS 2.0e-4f                // per-element screen-vs-np error bound (true ~5e-6; 40x margin)

typedef __bf16 bf16x8 __attribute__((ext_vector_type(8)));
typedef float  f32x4  __attribute__((ext_vector_type(4)));

__device__ __forceinline__ u16 f2bf(float f) {
  u32 u = __float_as_uint(f);
  u += 0x7fffu + ((u >> 16) & 1u);   // RNE
  return (u16)(u >> 16);
}
__device__ __forceinline__ float bf2f(u16 h) {
  return __uint_as_float(((u32)h) << 16);
}
__device__ __forceinline__ u32 fkey(float v) {   // order-preserving f32 -> u32
  u32 b = __float_as_uint(v);
  return (b & 0x80000000u) ? ~b : (b | 0x80000000u);
}
__device__ __forceinline__ float funkey(u32 o) {
  u32 b = (o & 0x80000000u) ? (o & 0x7FFFFFFFu) : ~o;
  return __uint_as_float(b);
}

// ---------------- fused preprocessing: convA | convB | transpose ----------------
__global__ __launch_bounds__(256) void prep(const float* __restrict__ tg_dec,
                                            const float* __restrict__ tf_base,
                                            const float* __restrict__ tf_expr,
                                            u16* __restrict__ Ah, u16* __restrict__ Al,
                                            u16* __restrict__ Bh, u16* __restrict__ Bl,
                                            float* __restrict__ tfT)
{
  __shared__ float tile[32][33];
  const int b = blockIdx.x;
  const int tid = threadIdx.x;
  if (b < 10816) {
    const float* src; u16 *hi, *lo; int valid_rows; int bb;
    if (b < 10048) { src = tg_dec; hi = Ah; lo = Al; valid_rows = G_ROWS; bb = b; }
    else           { src = tf_base; hi = Bh; lo = Bl; valid_rows = T_DIM; bb = b - 10048; }
    size_t i = ((size_t)bb * 256 + tid) * 4;
    int row = (int)(i >> 9);
    float4 a = make_float4(0.f, 0.f, 0.f, 0.f);
    if (row < valid_rows) a = *(const float4*)(src + i);
    float v[4] = {a.x, a.y, a.z, a.w};
    u16 h[4], l[4];
#pragma unroll
    for (int c = 0; c < 4; ++c) {
      h[c] = f2bf(v[c]);
      l[c] = f2bf(v[c] - bf2f(h[c]));
    }
    *(uint2*)(hi + i) = make_uint2((u32)h[0] | ((u32)h[1] << 16), (u32)h[2] | ((u32)h[3] << 16));
    *(uint2*)(lo + i) = make_uint2((u32)l[0] | ((u32)l[1] << 16), (u32)l[2] | ((u32)l[3] << 16));
  } else {
    const int t = b - 10816;
    const int x = tid & 31, y = tid >> 5;
    const int bt = (t % 48) * 32;
    const int bb = (t / 48) * 32;
#pragma unroll
    for (int i = 0; i < 32; i += 8) tile[y + i][x] = tf_expr[(size_t)(bb + y + i) * T_DIM + bt + x];
    __syncthreads();
#pragma unroll
    for (int i = 0; i < 32; i += 8) tfT[(size_t)(bt + y + i) * B_DIM + bb + x] = tile[x][y + i];
  }
}

// ---------------- async global -> LDS, 16B/lane ----------------
__device__ __forceinline__ void gl16(const u16* g, u16* l) {
  __builtin_amdgcn_global_load_lds((__attribute__((address_space(1))) void*)(void*)g,
                                   (__attribute__((address_space(3))) void*)l, 16, 0, 0);
}

// ---------------- screening GEMM: C ~= (Ah+Al)(Bh+Bl)^T via 3 bf16 MFMA terms ----------------
// R6-proven (102 us, MfmaUtil 40%): 256x256 tile, BK=32, 8 waves wave-tile 128x64,
// 4 half-buffers (128 KiB). 4 phases/K-tile; stage decoupling B(kt+1)@Ph1, A(kt+2)@Ph3;
// consume-wait vmcnt(4), vmcnt(0) only at kt=15.
#define NBX 6             // 1536 / 256
#define NWG 474           // 79 * 6

__global__ __launch_bounds__(512, 2) void gemm_split(const u16* __restrict__ Ah, const u16* __restrict__ Al,
                                                     const u16* __restrict__ Bh, const u16* __restrict__ Bl,
                                                     float* __restrict__ Sim)
{
  // u16 map: A-buf p at p*16384 (Ah 8192 | Al 8192); B-buf p at 32768 + p*16384 (Bh | Bl)
  __shared__ u16 sm[65536];   // 128 KiB

  // bijective XCD swizzle (m204; NWG % 8 == 2)
  const int orig = blockIdx.x;
  const int xcd  = orig & 7;
  const int q    = NWG >> 3, r = NWG & 7;
  const int wgid = (xcd < r ? xcd * (q + 1) : r * (q + 1) + (xcd - r) * q) + (orig >> 3);
  const int by   = wgid / NBX;
  const int bx   = wgid - by * NBX;
  const int bm0  = by * 256;
  const int bn0  = bx * 256;

  const int tid  = threadIdx.x;
  const int lane = tid & 63;
  const int wv   = tid >> 6;      // 0..7
  const int wm   = wv >> 2;       // 0..1 : wave row  (128-row strip)
  const int wn   = wv & 3;        // 0..3 : wave col  (64-col strip)
  const int la8  = lane << 3;     // u16 offset of this lane's 16B chunk in a subtile

  // staging roles: wave wv stages subtiles {2wv, 2wv+1}; subtile = 16 rows x 32 k,
  // 64 chunks of 16B in lane order (LDS dest linear: chunk l = lane l).
  const int sub  = wv << 1;
  const int srow = lane & 15;
  const int skc  = (lane >> 4) << 3;
  const u16* gA0  = Ah + (size_t)(bm0 + (sub + 0) * 16 + srow) * 512 + skc;
  const u16* gA1  = Ah + (size_t)(bm0 + (sub + 1) * 16 + srow) * 512 + skc;
  const u16* gAl0 = Al + (size_t)(bm0 + (sub + 0) * 16 + srow) * 512 + skc;
  const u16* gAl1 = Al + (size_t)(bm0 + (sub + 1) * 16 + srow) * 512 + skc;
  const u16* gB0  = Bh + (size_t)(bn0 + (sub + 0) * 16 + srow) * 512 + skc;
  const u16* gB1  = Bh + (size_t)(bn0 + (sub + 1) * 16 + srow) * 512 + skc;
  const u16* gBl0 = Bl + (size_t)(bn0 + (sub + 0) * 16 + srow) * 512 + skc;
  const u16* gBl1 = Bl + (size_t)(bn0 + (sub + 1) * 16 + srow) * 512 + skc;

#define STAGE_A(p, ktn) do {                                   \
    const size_t ko = (size_t)(ktn) << 5;                      \
    u16* d = sm + (p) * 16384 + sub * 512;                     \
    gl16(gA0 + ko,  d);                                        \
    gl16(gA1 + ko,  d + 512);                                  \
    gl16(gAl0 + ko, d + 8192);                                 \
    gl16(gAl1 + ko, d + 8192 + 512);                           \
  } while (0)
#define STAGE_B(p, ktn) do {                                   \
    const size_t ko = (size_t)(ktn) << 5;                      \
    u16* d = sm + 32768 + (p) * 16384 + sub * 512;             \
    gl16(gB0 + ko,  d);                                        \
    gl16(gB1 + ko,  d + 512);                                  \
    gl16(gBl0 + ko, d + 8192);                                 \
    gl16(gBl1 + ko, d + 8192 + 512);                           \
  } while (0)

  f32x4 acc[8][4];
#pragma unroll
  for (int i = 0; i < 8; ++i)
#pragma unroll
    for (int j = 0; j < 4; ++j) acc[i][j] = (f32x4){0.f, 0.f, 0.f, 0.f};

  bf16x8 aH[4], aL[4], bH[4], bL[4];

#define READ_A(rbA, half) do {                                                     \
    _Pragma("unroll")                                                              \
    for (int i = 0; i < 4; ++i) {                                                  \
      aH[i] = *(const bf16x8*)((rbA) + (wm * 8 + (half) * 4 + i) * 512 + la8);     \
      aL[i] = *(const bf16x8*)((rbA) + 8192 + (wm * 8 + (half) * 4 + i) * 512 + la8); \
    }                                                                              \
  } while (0)
#define READ_B(rbB, half) do {                                                     \
    _Pragma("unroll")                                                              \
    for (int i = 0; i < 2; ++i) {                                                  \
      bH[(half) * 2 + i] = *(const bf16x8*)((rbB) + (wn * 4 + (half) * 2 + i) * 512 + la8); \
      bL[(half) * 2 + i] = *(const bf16x8*)((rbB) + 8192 + (wn * 4 + (half) * 2 + i) * 512 + la8); \
    }                                                                              \
  } while (0)
#define MFMA_Q(qm, qn) do {                                                        \
    __builtin_amdgcn_s_setprio(1);                                                 \
    _Pragma("unroll")                                                              \
    for (int m2 = 0; m2 < 4; ++m2)                                                 \
      _Pragma("unroll")                                                            \
      for (int n2 = 0; n2 < 2; ++n2) {                                             \
        const int mi = (qm) * 4 + m2, ni = (qn) * 2 + n2;                          \
        acc[mi][ni] = __builtin_amdgcn_mfma_f32_16x16x32_bf16(aH[m2], bH[ni], acc[mi][ni], 0, 0, 0); \
        acc[mi][ni] = __builtin_amdgcn_mfma_f32_16x16x32_bf16(aH[m2], bL[ni], acc[mi][ni], 0, 0, 0); \
        acc[mi][ni] = __builtin_amdgcn_mfma_f32_16x16x32_bf16(aL[m2], bH[ni], acc[mi][ni], 0, 0, 0); \
      }                                                                            \
    __builtin_amdgcn_s_setprio(0);                                                 \
  } while (0)
#define LGKM0 do { asm volatile("s_waitcnt lgkmcnt(0)" ::: "memory"); __builtin_amdgcn_sched_barrier(0); } while (0)
#define BAR   do { __builtin_amdgcn_sched_barrier(0); __builtin_amdgcn_s_barrier(); } while (0)

  // prologue: A(0), B(0), A(1) in flight (12 loads/wave)
  STAGE_A(0, 0);
  STAGE_B(0, 0);
  STAGE_A(1, 1);

#pragma unroll 2
  for (int kt = 0; kt < 16; ++kt) {
    const u16* rbA = sm + (kt & 1) * 16384;
    const u16* rbB = sm + 32768 + (kt & 1) * 16384;

    // ---- Ph0: handshake (A(kt),B(kt) landed; A(kt+1) in flight); reads; MFMA Q00 ----
    if (kt < 15) asm volatile("s_waitcnt vmcnt(4)" ::: "memory");
    else         asm volatile("s_waitcnt vmcnt(0)" ::: "memory");
    BAR;
    READ_A(rbA, 0);
    READ_B(rbB, 0);
    LGKM0;
    MFMA_Q(0, 0);
    BAR;

    // ---- Ph1: stage B(kt+1) (buffer free since tile kt-1); read b-half 1; MFMA Q01 ----
    if (kt < 15) STAGE_B((kt + 1) & 1, kt + 1);
    READ_B(rbB, 1);
    LGKM0;
    MFMA_Q(0, 1);
    BAR;

    // ---- Ph2: read a-half 1; MFMA Q10 ----
    READ_A(rbA, 1);
    LGKM0;
    MFMA_Q(1, 0);
    BAR;                            // all waves' A-buf reads retired

    // ---- Ph3: stage A(kt+2) into A-buf[kt&1]; MFMA Q11 (pure register) ----
    if (kt < 14) STAGE_A(kt & 1, kt + 2);
    MFMA_Q(1, 1);
    // no barrier: Ph0(kt+1)'s vmcnt+barrier is the next sync point
  }
#undef STAGE_A
#undef STAGE_B
#undef READ_A
#undef READ_B
#undef MFMA_Q
#undef LGKM0
#undef BAR

  const int erow0 = bm0 + (wm << 7) + ((lane >> 4) << 2);
  const int ecol0 = bn0 + (wn << 6) + (lane & 15);
#pragma unroll
  for (int mi = 0; mi < 8; ++mi)
#pragma unroll
    for (int rr = 0; rr < 4; ++rr) {
      int row = erow0 + mi * 16 + rr;
      if (row < G_ROWS) {
#pragma unroll
        for (int ni = 0; ni < 4; ++ni)
          Sim[(size_t)row * T_DIM + ecol0 + ni * 16] = acc[mi][ni][rr] * SIM_SCALE;
      }
    }
}

// ---------------- helpers ----------------
__device__ __forceinline__ int count_ge(const float* v, float tau) {
  int c = 0;
#pragma unroll
  for (int j = 0; j < 24; ++j) c += (int)__popcll(__ballot(v[j] >= tau));
  return c;
}
// full 64-lane bitonic sort, descending by u64 key; returns this lane's sorted key
__device__ __forceinline__ u64 bitonic64_desc(u64 key, int lane) {
#pragma unroll
  for (int k = 2; k <= 64; k <<= 1) {
#pragma unroll
    for (int j = k >> 1; j > 0; j >>= 1) {
      u64 p = __shfl_xor(key, j, 64);
      bool lower = (lane & j) == 0;
      bool asc   = (lane & k) != 0;
      u64 mn = (key < p) ? key : p;
      u64 mx = (key < p) ? p : key;
      key = (lower == asc) ? mn : mx;
    }
  }
  return key;
}

// ---------------- fused top-k + combine (1 wave/row), MLP-restructured ----------------
// All 12 Sim/mask vec4 loads issued before any use; combine gathers batched x8
// (8 independent float4 loads in flight, 4 accumulator quads). Output via LDS transpose.
__global__ __launch_bounds__(256) void topk_combine(float* __restrict__ Sim, const int* __restrict__ mask,
                                                    const float* __restrict__ tg_dec,
                                                    const float* __restrict__ tf_base,
                                                    const float* __restrict__ tfT,
                                                    const float* __restrict__ scalep,
                                                    float* __restrict__ out0)
{
  __shared__ u32 cval[4][64];
  __shared__ int cidxs[4][64];
  __shared__ float sOut[4][256];
  const int lane = threadIdx.x & 63;
  const int wv   = threadIdx.x >> 6;
  const int g    = blockIdx.x * 4 + wv;
  float* row = Sim + (size_t)g * T_DIM;
  const int* mrow = mask + (size_t)g * T_DIM;

  // --- issue ALL 12 vec4 loads first (12 outstanding), then apply mask ---
  float4 q[6]; int4 mq[6];
#pragma unroll
  for (int j = 0; j < 6; ++j) q[j]  = *(const float4*)(row + j * 256 + lane * 4);
#pragma unroll
  for (int j = 0; j < 6; ++j) mq[j] = *(const int4*)(mrow + j * 256 + lane * 4);
  float v[24];
#pragma unroll
  for (int j = 0; j < 6; ++j) {
    v[j * 4 + 0] = mq[j].x ? q[j].x : -INFINITY;
    v[j * 4 + 1] = mq[j].y ? q[j].y : -INFINITY;
    v[j * 4 + 2] = mq[j].z ? q[j].z : -INFINITY;
    v[j * 4 + 3] = mq[j].w ? q[j].w : -INFINITY;
  }

  // --- parallel 6-threshold ladder count (pure VALU) + valid count ---
  const float TH0 = 1.25f, TH1 = 1.40f, TH2 = 1.55f, TH3 = 1.70f, TH4 = 1.85f, TH5 = 2.00f;
  int n0 = 0, n1 = 0, n2 = 0, n3 = 0, n4 = 0, n5 = 0, nv = 0;
#pragma unroll
  for (int j = 0; j < 24; ++j) {
    float x = v[j];
    n0 += (x >= TH0); n1 += (x >= TH1); n2 += (x >= TH2);
    n3 += (x >= TH3); n4 += (x >= TH4); n5 += (x >= TH5);
    nv += (x != -INFINITY);
  }
  u64 p0 = (u64)(u32)n0 | ((u64)(u32)n1 << 16) | ((u64)(u32)n2 << 32) | ((u64)(u32)n3 << 48);
  u64 p1 = (u64)(u32)n4 | ((u64)(u32)n5 << 16) | ((u64)(u32)nv << 32);
#pragma unroll
  for (int off = 32; off > 0; off >>= 1) {
    p0 += __shfl_xor(p0, off, 64);
    p1 += __shfl_xor(p1, off, 64);
  }
  int c[6];
  c[0] = (int)(p0 & 0xFFFF); c[1] = (int)((p0 >> 16) & 0xFFFF);
  c[2] = (int)((p0 >> 32) & 0xFFFF); c[3] = (int)((p0 >> 48) & 0xFFFF);
  c[4] = (int)(p1 & 0xFFFF); c[5] = (int)((p1 >> 16) & 0xFFFF);
  const int cvalid = (int)((p1 >> 32) & 0xFFFF);

  // --- pick largest threshold with count >= 33; fallback bisect for gaps/extremes (~1%) ---
  float tau; int cnt;
  if (cvalid <= 64) { tau = -3.0e38f; cnt = cvalid; }
  else {
    int is = -1;
#pragma unroll
    for (int i = 0; i < 6; ++i) if (c[i] >= 33) is = i;
    const float THv[7] = {TH0, TH1, TH2, TH3, TH4, TH5, 8.0f};
    if (is >= 0 && c[is] <= 64) { tau = THv[is]; cnt = c[is]; }
    else {
      float lo, hi;
      if (is < 0) { lo = -4.0f; hi = TH0; }
      else        { lo = THv[is]; hi = THv[is + 1]; }
      tau = lo; cnt = 1000;
      for (int it = 0; it < 16; ++it) {
        float mid = 0.5f * (lo + hi);
        int cm = count_ge(v, mid);
        if (cm > 64)      lo = mid;
        else if (cm < 33) hi = mid;
        else { tau = mid; cnt = cm; break; }
      }
      if (cnt == 1000) tau = lo;
    }
  }

  // --- ballot-prefix compaction into wave-private LDS ---
  int base = 0;
#pragma unroll
  for (int j = 0; j < 24; ++j) {
    bool pred = (v[j] >= tau);
    u64 bmc = __ballot(pred);
    int pos = base + (int)__popcll(bmc & ((1ull << lane) - 1ull));
    int idx = (j >> 2) * 256 + lane * 4 + (j & 3);
    if (pred && pos < 64) { cval[wv][pos] = fkey(v[j]); cidxs[wv][pos] = idx; }
    base += (int)__popcll(bmc);
  }
  const int cnt_eff = (base < 64) ? base : 64;

  u64 key = 0;
  if (lane < cnt_eff)
    key = ((u64)cval[wv][lane] << 32) | (u64)(u32)(~(u32)cidxs[wv][lane]);

  key = bitonic64_desc(key, lane);
  int   myidx = (int)(~(u32)key);
  float myv   = (key != 0) ? funkey((u32)(key >> 32)) : -INFINITY;

  // --- np-replica ONLY if the 31/32 cut is truly contested ---
  float v31 = __shfl(myv, 31, 64);
  float v32 = __shfl(myv, 32, 64);
  if (cnt_eff > TOPK && (v31 - v32) < 2.0f * BOUND_EPS) {
    bool flag = (lane < cnt_eff) &&
                (myv >= v32 - 2.0f * BOUND_EPS) && (myv <= v31 + 2.0f * BOUND_EPS);
    if (flag) {
      // bit-exact np replica: OpenBLAS sgemm sequential-K FMA chain, kc split 384|128
      const float* arow_g = tg_dec + (size_t)g * D_DIM;
      const float* brow2  = tf_base + (size_t)myidx * D_DIM;
      float s1 = 0.f, s2 = 0.f;
#pragma unroll 8
      for (int k = 0; k < 384; k += 4) {
        float4 av = *(const float4*)(arow_g + k);
        float4 bv = *(const float4*)(brow2 + k);
        s1 = fmaf(av.x, bv.x, s1); s1 = fmaf(av.y, bv.y, s1);
        s1 = fmaf(av.z, bv.z, s1); s1 = fmaf(av.w, bv.w, s1);
      }
#pragma unroll 8
      for (int k = 384; k < 512; k += 4) {
        float4 av = *(const float4*)(arow_g + k);
        float4 bv = *(const float4*)(brow2 + k);
        s2 = fmaf(av.x, bv.x, s2); s2 = fmaf(av.y, bv.y, s2);
        s2 = fmaf(av.z, bv.z, s2); s2 = fmaf(av.w, bv.w, s2);
      }
      myv = (s1 + s2) / SQRT_D;
      key = ((u64)fkey(myv) << 32) | (u64)(u32)(~(u32)myidx);
    }
    key = bitonic64_desc(key, lane);
    myidx = (int)(~(u32)key);
    myv   = (key != 0) ? funkey((u32)(key >> 32)) : -INFINITY;
  }

  // --- weights from sorted lanes 0..31 ---
  const bool selme = (lane < TOPK) && (lane < cnt_eff);
  float mx = __shfl(myv, 0, 64);
  float e = selme ? __expf(myv - mx) : 0.f;
  float E = e;
#pragma unroll
  for (int off = 32; off > 0; off >>= 1) E += __shfl_xor(E, off, 64);
  float rden = (E > 0.f) ? (1.f / E) : 0.f;
  float w = e * rden;

  // --- dense zero write (issues early; drains before scatter below) ---
  const float4 z4 = make_float4(0.f, 0.f, 0.f, 0.f);
#pragma unroll
  for (int j = 0; j < 6; ++j) *(float4*)(row + j * 256 + lane * 4) = z4;

  // --- fused combine, batched x8: acc[c] = sum_k w_k * tfT[idx_k, lane*4+c] ---
  float a0 = 0.f, a1 = 0.f, a2 = 0.f, a3 = 0.f;
  float b0 = 0.f, b1 = 0.f, b2 = 0.f, b3 = 0.f;
#pragma unroll
  for (int kb = 0; kb < 4; ++kb) {
    float wk[8]; int ik[8];
#pragma unroll
    for (int u = 0; u < 8; ++u) {
      wk[u] = __shfl(w, kb * 8 + u, 64);
      int t = __shfl(myidx, kb * 8 + u, 64);
      ik[u] = (wk[u] > 0.f) ? t : 0;     // garbage-idx guard: weight 0 contributes 0
    }
    float4 vv[8];
#pragma unroll
    for (int u = 0; u < 8; ++u)
      vv[u] = *(const float4*)(tfT + (size_t)ik[u] * B_DIM + lane * 4);
#pragma unroll
    for (int u = 0; u < 8; u += 2) {
      a0 = fmaf(wk[u], vv[u].x, a0);     a1 = fmaf(wk[u], vv[u].y, a1);
      a2 = fmaf(wk[u], vv[u].z, a2);     a3 = fmaf(wk[u], vv[u].w, a3);
      b0 = fmaf(wk[u+1], vv[u+1].x, b0); b1 = fmaf(wk[u+1], vv[u+1].y, b1);
      b2 = fmaf(wk[u+1], vv[u+1].z, b2); b3 = fmaf(wk[u+1], vv[u+1].w, b3);
    }
  }
  a0 += b0; a1 += b1; a2 += b2; a3 += b3;

  const float scale = scalep[0];
  // LDS transpose: sOut[wv][b] so the out0 write is float4 per thread (16B chunks, L2-combined)
  *(float4*)(&sOut[wv][lane * 4]) = make_float4(scale * a0, scale * a1, scale * a2, scale * a3);
  __syncthreads();
  {
    const int t = threadIdx.x;         // b index
    const int g0 = blockIdx.x * 4;
    float4 o = make_float4(sOut[0][t], sOut[1][t], sOut[2][t], sOut[3][t]);
    *(float4*)(out0 + (size_t)t * G_ROWS + g0) = o;
  }

  // --- drain zeros, then sparse scatter of the 32 weights ---
  asm volatile("s_waitcnt vmcnt(0)" ::: "memory");
  if (selme) row[myidx] = w;
}

extern "C" void kernel_launch(void* const* d_in, const int* in_sizes, int n_in,
                              void* d_out, int out_size, void* d_ws, size_t ws_size,
                              hipStream_t stream)
{
  const float* tg_dec     = (const float*)d_in[0];
  const float* tf_base    = (const float*)d_in[1];
  const float* tf_expr    = (const float*)d_in[2];
  const int*   motif_mask = (const int*)d_in[3];
  const float* scale      = (const float*)d_in[4];

  float* out0 = (float*)d_out;                           // [B, G]
  float* attn = out0 + (size_t)B_DIM * G_ROWS;           // [G, T] — Sim scratch, overwritten in place

  char* ws = (char*)d_ws;
  u16*   Ah    = (u16*)(ws);                             // G_PAD*512 bf16
  u16*   Al    = (u16*)(ws + 20578304);
  u16*   Bh    = (u16*)(ws + 41156608);                  // 1536*512 bf16
  u16*   Bl    = (u16*)(ws + 42729472);
  float* tfT   = (float*)(ws + 44302336);                // [T, B] f32

  prep<<<11200, 256, 0, stream>>>(tg_dec, tf_base, tf_expr, Ah, Al, Bh, Bl, tfT);
  gemm_split<<<NWG, 512, 0, stream>>>(Ah, Al, Bh, Bl, attn);
  topk_combine<<<5000, 256, 0, stream>>>(attn, motif_mask, tg_dec, tf_base, tfT, scale, out0);
}

// Round 9
// 415.163 us; speedup vs baseline: 1.0999x; 1.0157x over previous
//
#include <hip/hip_runtime.h>
#include <cstdint>

typedef unsigned short u16;
typedef unsigned int   u32;
typedef unsigned long long u64;

#define G_ROWS 20000
#define G_PAD  20096      // 157 * 128 (conv padding; gemm over-reads past this, guarded on store)
#define T_DIM  1536
#define D_DIM  512
#define B_DIM  256
#define TOPK   32
#define SIM_SCALE 0.04419417382415922f   // 1/sqrt(512), screening only
#define SQRT_D    22.62741699796952f     // f32(math.sqrt(512)) — np divides by this
#define BOUND_EPS 2.0e-4f                // per-element screen-vs-np error bound (true ~5e-6; 40x margin)

typedef __bf16 bf16x8 __attribute__((ext_vector_type(8)));
typedef float  f32x4  __attribute__((ext_vector_type(4)));

__device__ __forceinline__ u16 f2bf(float f) {
  u32 u = __float_as_uint(f);
  u += 0x7fffu + ((u >> 16) & 1u);   // RNE
  return (u16)(u >> 16);
}
__device__ __forceinline__ float bf2f(u16 h) {
  return __uint_as_float(((u32)h) << 16);
}
__device__ __forceinline__ u32 fkey(float v) {   // order-preserving f32 -> u32
  u32 b = __float_as_uint(v);
  return (b & 0x80000000u) ? ~b : (b | 0x80000000u);
}
__device__ __forceinline__ float funkey(u32 o) {
  u32 b = (o & 0x80000000u) ? (o & 0x7FFFFFFFu) : ~o;
  return __uint_as_float(b);
}

// ---------------- fused preprocessing: convA | convB | transpose ----------------
__global__ __launch_bounds__(256) void prep(const float* __restrict__ tg_dec,
                                            const float* __restrict__ tf_base,
                                            const float* __restrict__ tf_expr,
                                            u16* __restrict__ Ah, u16* __restrict__ Al,
                                            u16* __restrict__ Bh, u16* __restrict__ Bl,
                                            float* __restrict__ tfT)
{
  __shared__ float tile[32][33];
  const int b = blockIdx.x;
  const int tid = threadIdx.x;
  if (b < 10816) {
    const float* src; u16 *hi, *lo; int valid_rows; int bb;
    if (b < 10048) { src = tg_dec; hi = Ah; lo = Al; valid_rows = G_ROWS; bb = b; }
    else           { src = tf_base; hi = Bh; lo = Bl; valid_rows = T_DIM; bb = b - 10048; }
    size_t i = ((size_t)bb * 256 + tid) * 4;
    int row = (int)(i >> 9);
    float4 a = make_float4(0.f, 0.f, 0.f, 0.f);
    if (row < valid_rows) a = *(const float4*)(src + i);
    float v[4] = {a.x, a.y, a.z, a.w};
    u16 h[4], l[4];
#pragma unroll
    for (int c = 0; c < 4; ++c) {
      h[c] = f2bf(v[c]);
      l[c] = f2bf(v[c] - bf2f(h[c]));
    }
    *(uint2*)(hi + i) = make_uint2((u32)h[0] | ((u32)h[1] << 16), (u32)h[2] | ((u32)h[3] << 16));
    *(uint2*)(lo + i) = make_uint2((u32)l[0] | ((u32)l[1] << 16), (u32)l[2] | ((u32)l[3] << 16));
  } else {
    const int t = b - 10816;
    const int x = tid & 31, y = tid >> 5;
    const int bt = (t % 48) * 32;
    const int bb = (t / 48) * 32;
#pragma unroll
    for (int i = 0; i < 32; i += 8) tile[y + i][x] = tf_expr[(size_t)(bb + y + i) * T_DIM + bt + x];
    __syncthreads();
#pragma unroll
    for (int i = 0; i < 32; i += 8) tfT[(size_t)(bt + y + i) * B_DIM + bb + x] = tile[x][y + i];
  }
}

// ---------------- async global -> LDS, 16B/lane ----------------
__device__ __forceinline__ void gl16(const u16* g, u16* l) {
  __builtin_amdgcn_global_load_lds((__attribute__((address_space(1))) void*)(void*)g,
                                   (__attribute__((address_space(3))) void*)l, 16, 0, 0);
}

// ---------------- screening GEMM: C ~= (Ah+Al)(Bh+Bl)^T via 3 bf16 MFMA terms ----------------
// R6-proven (102 us, MfmaUtil 40%): 256x256 tile, BK=32, 8 waves wave-tile 128x64,
// 4 half-buffers (128 KiB). 4 phases/K-tile; stage decoupling B(kt+1)@Ph1, A(kt+2)@Ph3;
// consume-wait vmcnt(4), vmcnt(0) only at kt=15.
#define NBX 6             // 1536 / 256
#define NWG 474           // 79 * 6

__global__ __launch_bounds__(512, 2) void gemm_split(const u16* __restrict__ Ah, const u16* __restrict__ Al,
                                                     const u16* __restrict__ Bh, const u16* __restrict__ Bl,
                                                     float* __restrict__ Sim)
{
  // u16 map: A-buf p at p*16384 (Ah 8192 | Al 8192); B-buf p at 32768 + p*16384 (Bh | Bl)
  __shared__ u16 sm[65536];   // 128 KiB

  // bijective XCD swizzle (m204; NWG % 8 == 2)
  const int orig = blockIdx.x;
  const int xcd  = orig & 7;
  const int q    = NWG >> 3, r = NWG & 7;
  const int wgid = (xcd < r ? xcd * (q + 1) : r * (q + 1) + (xcd - r) * q) + (orig >> 3);
  const int by   = wgid / NBX;
  const int bx   = wgid - by * NBX;
  const int bm0  = by * 256;
  const int bn0  = bx * 256;

  const int tid  = threadIdx.x;
  const int lane = tid & 63;
  const int wv   = tid >> 6;      // 0..7
  const int wm   = wv >> 2;       // 0..1 : wave row  (128-row strip)
  const int wn   = wv & 3;        // 0..3 : wave col  (64-col strip)
  const int la8  = lane << 3;     // u16 offset of this lane's 16B chunk in a subtile

  // staging roles: wave wv stages subtiles {2wv, 2wv+1}; subtile = 16 rows x 32 k,
  // 64 chunks of 16B in lane order (LDS dest linear: chunk l = lane l).
  const int sub  = wv << 1;
  const int srow = lane & 15;
  const int skc  = (lane >> 4) << 3;
  const u16* gA0  = Ah + (size_t)(bm0 + (sub + 0) * 16 + srow) * 512 + skc;
  const u16* gA1  = Ah + (size_t)(bm0 + (sub + 1) * 16 + srow) * 512 + skc;
  const u16* gAl0 = Al + (size_t)(bm0 + (sub + 0) * 16 + srow) * 512 + skc;
  const u16* gAl1 = Al + (size_t)(bm0 + (sub + 1) * 16 + srow) * 512 + skc;
  const u16* gB0  = Bh + (size_t)(bn0 + (sub + 0) * 16 + srow) * 512 + skc;
  const u16* gB1  = Bh + (size_t)(bn0 + (sub + 1) * 16 + srow) * 512 + skc;
  const u16* gBl0 = Bl + (size_t)(bn0 + (sub + 0) * 16 + srow) * 512 + skc;
  const u16* gBl1 = Bl + (size_t)(bn0 + (sub + 1) * 16 + srow) * 512 + skc;

#define STAGE_A(p, ktn) do {                                   \
    const size_t ko = (size_t)(ktn) << 5;                      \
    u16* d = sm + (p) * 16384 + sub * 512;                     \
    gl16(gA0 + ko,  d);                                        \
    gl16(gA1 + ko,  d + 512);                                  \
    gl16(gAl0 + ko, d + 8192);                                 \
    gl16(gAl1 + ko, d + 8192 + 512);                           \
  } while (0)
#define STAGE_B(p, ktn) do {                                   \
    const size_t ko = (size_t)(ktn) << 5;                      \
    u16* d = sm + 32768 + (p) * 16384 + sub * 512;             \
    gl16(gB0 + ko,  d);                                        \
    gl16(gB1 + ko,  d + 512);                                  \
    gl16(gBl0 + ko, d + 8192);                                 \
    gl16(gBl1 + ko, d + 8192 + 512);                           \
  } while (0)

  f32x4 acc[8][4];
#pragma unroll
  for (int i = 0; i < 8; ++i)
#pragma unroll
    for (int j = 0; j < 4; ++j) acc[i][j] = (f32x4){0.f, 0.f, 0.f, 0.f};

  bf16x8 aH[4], aL[4], bH[4], bL[4];

#define READ_A(rbA, half) do {                                                     \
    _Pragma("unroll")                                                              \
    for (int i = 0; i < 4; ++i) {                                                  \
      aH[i] = *(const bf16x8*)((rbA) + (wm * 8 + (half) * 4 + i) * 512 + la8);     \
      aL[i] = *(const bf16x8*)((rbA) + 8192 + (wm * 8 + (half) * 4 + i) * 512 + la8); \
    }                                                                              \
  } while (0)
#define READ_B(rbB, half) do {                                                     \
    _Pragma("unroll")                                                              \
    for (int i = 0; i < 2; ++i) {                                                  \
      bH[(half) * 2 + i] = *(const bf16x8*)((rbB) + (wn * 4 + (half) * 2 + i) * 512 + la8); \
      bL[(half) * 2 + i] = *(const bf16x8*)((rbB) + 8192 + (wn * 4 + (half) * 2 + i) * 512 + la8); \
    }                                                                              \
  } while (0)
#define MFMA_Q(qm, qn) do {                                                        \
    __builtin_amdgcn_s_setprio(1);                                                 \
    _Pragma("unroll")                                                              \
    for (int m2 = 0; m2 < 4; ++m2)                                                 \
      _Pragma("unroll")                                                            \
      for (int n2 = 0; n2 < 2; ++n2) {                                             \
        const int mi = (qm) * 4 + m2, ni = (qn) * 2 + n2;                          \
        acc[mi][ni] = __builtin_amdgcn_mfma_f32_16x16x32_bf16(aH[m2], bH[ni], acc[mi][ni], 0, 0, 0); \
        acc[mi][ni] = __builtin_amdgcn_mfma_f32_16x16x32_bf16(aH[m2], bL[ni], acc[mi][ni], 0, 0, 0); \
        acc[mi][ni] = __builtin_amdgcn_mfma_f32_16x16x32_bf16(aL[m2], bH[ni], acc[mi][ni], 0, 0, 0); \
      }                                                                            \
    __builtin_amdgcn_s_setprio(0);                                                 \
  } while (0)
#define LGKM0 do { asm volatile("s_waitcnt lgkmcnt(0)" ::: "memory"); __builtin_amdgcn_sched_barrier(0); } while (0)
#define BAR   do { __builtin_amdgcn_sched_barrier(0); __builtin_amdgcn_s_barrier(); } while (0)

  // prologue: A(0), B(0), A(1) in flight (12 loads/wave)
  STAGE_A(0, 0);
  STAGE_B(0, 0);
  STAGE_A(1, 1);

#pragma unroll 2
  for (int kt = 0; kt < 16; ++kt) {
    const u16* rbA = sm + (kt & 1) * 16384;
    const u16* rbB = sm + 32768 + (kt & 1) * 16384;

    // ---- Ph0: handshake (A(kt),B(kt) landed; A(kt+1) in flight); reads; MFMA Q00 ----
    if (kt < 15) asm volatile("s_waitcnt vmcnt(4)" ::: "memory");
    else         asm volatile("s_waitcnt vmcnt(0)" ::: "memory");
    BAR;
    READ_A(rbA, 0);
    READ_B(rbB, 0);
    LGKM0;
    MFMA_Q(0, 0);
    BAR;

    // ---- Ph1: stage B(kt+1) (buffer free since tile kt-1); read b-half 1; MFMA Q01 ----
    if (kt < 15) STAGE_B((kt + 1) & 1, kt + 1);
    READ_B(rbB, 1);
    LGKM0;
    MFMA_Q(0, 1);
    BAR;

    // ---- Ph2: read a-half 1; MFMA Q10 ----
    READ_A(rbA, 1);
    LGKM0;
    MFMA_Q(1, 0);
    BAR;                            // all waves' A-buf reads retired

    // ---- Ph3: stage A(kt+2) into A-buf[kt&1]; MFMA Q11 (pure register) ----
    if (kt < 14) STAGE_A(kt & 1, kt + 2);
    MFMA_Q(1, 1);
    // no barrier: Ph0(kt+1)'s vmcnt+barrier is the next sync point
  }
#undef STAGE_A
#undef STAGE_B
#undef READ_A
#undef READ_B
#undef MFMA_Q
#undef LGKM0
#undef BAR

  const int erow0 = bm0 + (wm << 7) + ((lane >> 4) << 2);
  const int ecol0 = bn0 + (wn << 6) + (lane & 15);
#pragma unroll
  for (int mi = 0; mi < 8; ++mi)
#pragma unroll
    for (int rr = 0; rr < 4; ++rr) {
      int row = erow0 + mi * 16 + rr;
      if (row < G_ROWS) {
#pragma unroll
        for (int ni = 0; ni < 4; ++ni)
          Sim[(size_t)row * T_DIM + ecol0 + ni * 16] = acc[mi][ni][rr] * SIM_SCALE;
      }
    }
}

// ---------------- helpers ----------------
__device__ __forceinline__ int count_ge(const float* v, float tau) {
  int c = 0;
#pragma unroll
  for (int j = 0; j < 24; ++j) c += (int)__popcll(__ballot(v[j] >= tau));
  return c;
}
// dual-row 64-lane bitonic sort (two independent keys interleaved to hide shfl latency)
__device__ __forceinline__ void bitonic64_desc2(u64& kA, u64& kB, int lane) {
#pragma unroll
  for (int k = 2; k <= 64; k <<= 1) {
#pragma unroll
    for (int j = k >> 1; j > 0; j >>= 1) {
      u64 pA = __shfl_xor(kA, j, 64);
      u64 pB = __shfl_xor(kB, j, 64);
      bool lower = (lane & j) == 0;
      bool asc   = (lane & k) != 0;
      u64 mnA = (kA < pA) ? kA : pA, mxA = (kA < pA) ? pA : kA;
      u64 mnB = (kB < pB) ? kB : pB, mxB = (kB < pB) ? pB : kB;
      kA = (lower == asc) ? mnA : mxA;
      kB = (lower == asc) ? mnB : mxB;
    }
  }
}
__device__ __forceinline__ u64 bitonic64_desc(u64 key, int lane) {
#pragma unroll
  for (int k = 2; k <= 64; k <<= 1) {
#pragma unroll
    for (int j = k >> 1; j > 0; j >>= 1) {
      u64 p = __shfl_xor(key, j, 64);
      bool lower = (lane & j) == 0;
      bool asc   = (lane & k) != 0;
      u64 mn = (key < p) ? key : p;
      u64 mx = (key < p) ? p : key;
      key = (lower == asc) ? mn : mx;
    }
  }
  return key;
}

// per-row tau selection from ladder counts (inlined; fallback bisect is rare)
__device__ __forceinline__ float pick_tau(const int* c, int cvalid, const float* v) {
  const float TH0 = 1.25f, TH1 = 1.40f, TH2 = 1.55f, TH3 = 1.70f, TH4 = 1.85f, TH5 = 2.00f;
  if (cvalid <= 64) return -3.0e38f;
  int is = -1;
#pragma unroll
  for (int i = 0; i < 6; ++i) if (c[i] >= 33) is = i;
  const float THv[7] = {TH0, TH1, TH2, TH3, TH4, TH5, 8.0f};
  if (is >= 0 && c[is] <= 64) return THv[is];
  float lo, hi;
  if (is < 0) { lo = -4.0f; hi = TH0; }
  else        { lo = THv[is]; hi = THv[is + 1]; }
  float tau = lo; int cnt = 1000;
  for (int it = 0; it < 16; ++it) {
    float mid = 0.5f * (lo + hi);
    int cm = count_ge(v, mid);
    if (cm > 64)      lo = mid;
    else if (cm < 33) hi = mid;
    else { tau = mid; cnt = cm; break; }
  }
  if (cnt == 1000) tau = lo;
  return tau;
}

// bit-exact np replica dot product (OpenBLAS sgemm chain, kc split 384|128)
__device__ __forceinline__ float np_dot(const float* __restrict__ arow, const float* __restrict__ brow) {
  float s1 = 0.f, s2 = 0.f;
#pragma unroll 8
  for (int k = 0; k < 384; k += 4) {
    float4 av = *(const float4*)(arow + k);
    float4 bv = *(const float4*)(brow + k);
    s1 = fmaf(av.x, bv.x, s1); s1 = fmaf(av.y, bv.y, s1);
    s1 = fmaf(av.z, bv.z, s1); s1 = fmaf(av.w, bv.w, s1);
  }
#pragma unroll 8
  for (int k = 384; k < 512; k += 4) {
    float4 av = *(const float4*)(arow + k);
    float4 bv = *(const float4*)(brow + k);
    s2 = fmaf(av.x, bv.x, s2); s2 = fmaf(av.y, bv.y, s2);
    s2 = fmaf(av.z, bv.z, s2); s2 = fmaf(av.w, bv.w, s2);
  }
  return (s1 + s2) / SQRT_D;
}

// ---------------- fused top-k + combine, 2 rows per wave (ILP) ----------------
// Each wave processes rows 2wv, 2wv+1 of an 8-row block; the two rows' dependency chains
// (loads, ladder, shfl-reduce, compaction, bitonic, combine gathers) are interleaved so
// each row's latency hides under the other's work. Output via LDS transpose (8 rows/block).
__global__ __launch_bounds__(256) void topk_combine(float* __restrict__ Sim, const int* __restrict__ mask,
                                                    const float* __restrict__ tg_dec,
                                                    const float* __restrict__ tf_base,
                                                    const float* __restrict__ tfT,
                                                    const float* __restrict__ scalep,
                                                    float* __restrict__ out0)
{
  __shared__ u32 cval[8][64];
  __shared__ int cidxs[8][64];
  __shared__ float sOut[8][256];
  const int lane = threadIdx.x & 63;
  const int wv   = threadIdx.x >> 6;
  const int gA   = blockIdx.x * 8 + wv * 2;
  const int gB   = gA + 1;
  float* rowA = Sim + (size_t)gA * T_DIM;
  float* rowB = Sim + (size_t)gB * T_DIM;
  const int* mrowA = mask + (size_t)gA * T_DIM;
  const int* mrowB = mask + (size_t)gB * T_DIM;

  // --- issue ALL 24 vec4 loads (both rows) before any use ---
  float4 qA[6], qB[6]; int4 mA[6], mB[6];
#pragma unroll
  for (int j = 0; j < 6; ++j) qA[j] = *(const float4*)(rowA + j * 256 + lane * 4);
#pragma unroll
  for (int j = 0; j < 6; ++j) qB[j] = *(const float4*)(rowB + j * 256 + lane * 4);
#pragma unroll
  for (int j = 0; j < 6; ++j) mA[j] = *(const int4*)(mrowA + j * 256 + lane * 4);
#pragma unroll
  for (int j = 0; j < 6; ++j) mB[j] = *(const int4*)(mrowB + j * 256 + lane * 4);

  float vA[24], vB[24];
#pragma unroll
  for (int j = 0; j < 6; ++j) {
    vA[j*4+0] = mA[j].x ? qA[j].x : -INFINITY;
    vA[j*4+1] = mA[j].y ? qA[j].y : -INFINITY;
    vA[j*4+2] = mA[j].z ? qA[j].z : -INFINITY;
    vA[j*4+3] = mA[j].w ? qA[j].w : -INFINITY;
    vB[j*4+0] = mB[j].x ? qB[j].x : -INFINITY;
    vB[j*4+1] = mB[j].y ? qB[j].y : -INFINITY;
    vB[j*4+2] = mB[j].z ? qB[j].z : -INFINITY;
    vB[j*4+3] = mB[j].w ? qB[j].w : -INFINITY;
  }

  // --- dual ladder count ---
  const float TH0 = 1.25f, TH1 = 1.40f, TH2 = 1.55f, TH3 = 1.70f, TH4 = 1.85f, TH5 = 2.00f;
  int nA0=0,nA1=0,nA2=0,nA3=0,nA4=0,nA5=0,nAv=0;
  int nB0=0,nB1=0,nB2=0,nB3=0,nB4=0,nB5=0,nBv=0;
#pragma unroll
  for (int j = 0; j < 24; ++j) {
    float x = vA[j], y = vB[j];
    nA0 += (x >= TH0); nA1 += (x >= TH1); nA2 += (x >= TH2);
    nA3 += (x >= TH3); nA4 += (x >= TH4); nA5 += (x >= TH5);
    nAv += (x != -INFINITY);
    nB0 += (y >= TH0); nB1 += (y >= TH1); nB2 += (y >= TH2);
    nB3 += (y >= TH3); nB4 += (y >= TH4); nB5 += (y >= TH5);
    nBv += (y != -INFINITY);
  }
  u64 pA0 = (u64)(u32)nA0 | ((u64)(u32)nA1 << 16) | ((u64)(u32)nA2 << 32) | ((u64)(u32)nA3 << 48);
  u64 pA1 = (u64)(u32)nA4 | ((u64)(u32)nA5 << 16) | ((u64)(u32)nAv << 32);
  u64 pB0 = (u64)(u32)nB0 | ((u64)(u32)nB1 << 16) | ((u64)(u32)nB2 << 32) | ((u64)(u32)nB3 << 48);
  u64 pB1 = (u64)(u32)nB4 | ((u64)(u32)nB5 << 16) | ((u64)(u32)nBv << 32);
#pragma unroll
  for (int off = 32; off > 0; off >>= 1) {
    pA0 += __shfl_xor(pA0, off, 64);
    pB0 += __shfl_xor(pB0, off, 64);
    pA1 += __shfl_xor(pA1, off, 64);
    pB1 += __shfl_xor(pB1, off, 64);
  }
  int cA[6], cB[6];
  cA[0]=(int)(pA0&0xFFFF); cA[1]=(int)((pA0>>16)&0xFFFF); cA[2]=(int)((pA0>>32)&0xFFFF);
  cA[3]=(int)((pA0>>48)&0xFFFF); cA[4]=(int)(pA1&0xFFFF); cA[5]=(int)((pA1>>16)&0xFFFF);
  const int cAv = (int)((pA1 >> 32) & 0xFFFF);
  cB[0]=(int)(pB0&0xFFFF); cB[1]=(int)((pB0>>16)&0xFFFF); cB[2]=(int)((pB0>>32)&0xFFFF);
  cB[3]=(int)((pB0>>48)&0xFFFF); cB[4]=(int)(pB1&0xFFFF); cB[5]=(int)((pB1>>16)&0xFFFF);
  const int cBv = (int)((pB1 >> 32) & 0xFFFF);

  const float tauA = pick_tau(cA, cAv, vA);
  const float tauB = pick_tau(cB, cBv, vB);

  // --- dual ballot-prefix compaction ---
  const int slA = wv * 2, slB = wv * 2 + 1;
  int baseA = 0, baseB = 0;
#pragma unroll
  for (int j = 0; j < 24; ++j) {
    int idx = (j >> 2) * 256 + lane * 4 + (j & 3);
    bool prA = (vA[j] >= tauA);
    bool prB = (vB[j] >= tauB);
    u64 bmA = __ballot(prA);
    u64 bmB = __ballot(prB);
    int posA = baseA + (int)__popcll(bmA & ((1ull << lane) - 1ull));
    int posB = baseB + (int)__popcll(bmB & ((1ull << lane) - 1ull));
    if (prA && posA < 64) { cval[slA][posA] = fkey(vA[j]); cidxs[slA][posA] = idx; }
    if (prB && posB < 64) { cval[slB][posB] = fkey(vB[j]); cidxs[slB][posB] = idx; }
    baseA += (int)__popcll(bmA);
    baseB += (int)__popcll(bmB);
  }
  const int cntA = (baseA < 64) ? baseA : 64;
  const int cntB = (baseB < 64) ? baseB : 64;

  u64 keyA = 0, keyB = 0;
  if (lane < cntA) keyA = ((u64)cval[slA][lane] << 32) | (u64)(u32)(~(u32)cidxs[slA][lane]);
  if (lane < cntB) keyB = ((u64)cval[slB][lane] << 32) | (u64)(u32)(~(u32)cidxs[slB][lane]);

  // --- dual bitonic sort ---
  bitonic64_desc2(keyA, keyB, lane);
  int   idxA = (int)(~(u32)keyA);
  float valA = (keyA != 0) ? funkey((u32)(keyA >> 32)) : -INFINITY;
  int   idxB = (int)(~(u32)keyB);
  float valB = (keyB != 0) ? funkey((u32)(keyB >> 32)) : -INFINITY;

  // --- np-replica (rare, per row) ---
  {
    float v31 = __shfl(valA, 31, 64);
    float v32 = __shfl(valA, 32, 64);
    if (cntA > TOPK && (v31 - v32) < 2.0f * BOUND_EPS) {
      bool flag = (lane < cntA) &&
                  (valA >= v32 - 2.0f * BOUND_EPS) && (valA <= v31 + 2.0f * BOUND_EPS);
      if (flag) {
        valA = np_dot(tg_dec + (size_t)gA * D_DIM, tf_base + (size_t)idxA * D_DIM);
        keyA = ((u64)fkey(valA) << 32) | (u64)(u32)(~(u32)idxA);
      }
      keyA = bitonic64_desc(keyA, lane);
      idxA = (int)(~(u32)keyA);
      valA = (keyA != 0) ? funkey((u32)(keyA >> 32)) : -INFINITY;
    }
  }
  {
    float v31 = __shfl(valB, 31, 64);
    float v32 = __shfl(valB, 32, 64);
    if (cntB > TOPK && (v31 - v32) < 2.0f * BOUND_EPS) {
      bool flag = (lane < cntB) &&
                  (valB >= v32 - 2.0f * BOUND_EPS) && (valB <= v31 + 2.0f * BOUND_EPS);
      if (flag) {
        valB = np_dot(tg_dec + (size_t)gB * D_DIM, tf_base + (size_t)idxB * D_DIM);
        keyB = ((u64)fkey(valB) << 32) | (u64)(u32)(~(u32)idxB);
      }
      keyB = bitonic64_desc(keyB, lane);
      idxB = (int)(~(u32)keyB);
      valB = (keyB != 0) ? funkey((u32)(keyB >> 32)) : -INFINITY;
    }
  }

  // --- dual softmax over sorted lanes 0..31 ---
  const bool selA = (lane < TOPK) && (lane < cntA);
  const bool selB = (lane < TOPK) && (lane < cntB);
  float mxA = __shfl(valA, 0, 64);
  float mxB = __shfl(valB, 0, 64);
  float eA = selA ? __expf(valA - mxA) : 0.f;
  float eB = selB ? __expf(valB - mxB) : 0.f;
  float EA = eA, EB = eB;
#pragma unroll
  for (int off = 32; off > 0; off >>= 1) {
    EA += __shfl_xor(EA, off, 64);
    EB += __shfl_xor(EB, off, 64);
  }
  float wA = eA * ((EA > 0.f) ? (1.f / EA) : 0.f);
  float wB = eB * ((EB > 0.f) ? (1.f / EB) : 0.f);

  // --- dense zero writes (issue early; drain before scatter) ---
  const float4 z4 = make_float4(0.f, 0.f, 0.f, 0.f);
#pragma unroll
  for (int j = 0; j < 6; ++j) {
    *(float4*)(rowA + j * 256 + lane * 4) = z4;
    *(float4*)(rowB + j * 256 + lane * 4) = z4;
  }

  // --- dual combine, batched x8 per row (16 gathers in flight) ---
  float aA0=0.f,aA1=0.f,aA2=0.f,aA3=0.f;
  float aB0=0.f,aB1=0.f,aB2=0.f,aB3=0.f;
#pragma unroll
  for (int kb = 0; kb < 4; ++kb) {
    float wkA[8], wkB[8]; int ikA[8], ikB[8];
#pragma unroll
    for (int u = 0; u < 8; ++u) {
      wkA[u] = __shfl(wA, kb * 8 + u, 64);
      wkB[u] = __shfl(wB, kb * 8 + u, 64);
      int tA = __shfl(idxA, kb * 8 + u, 64);
      int tB = __shfl(idxB, kb * 8 + u, 64);
      ikA[u] = (wkA[u] > 0.f) ? tA : 0;
      ikB[u] = (wkB[u] > 0.f) ? tB : 0;
    }
    float4 vvA[8], vvB[8];
#pragma unroll
    for (int u = 0; u < 8; ++u) {
      vvA[u] = *(const float4*)(tfT + (size_t)ikA[u] * B_DIM + lane * 4);
      vvB[u] = *(const float4*)(tfT + (size_t)ikB[u] * B_DIM + lane * 4);
    }
#pragma unroll
    for (int u = 0; u < 8; ++u) {
      aA0 = fmaf(wkA[u], vvA[u].x, aA0); aA1 = fmaf(wkA[u], vvA[u].y, aA1);
      aA2 = fmaf(wkA[u], vvA[u].z, aA2); aA3 = fmaf(wkA[u], vvA[u].w, aA3);
      aB0 = fmaf(wkB[u], vvB[u].x, aB0); aB1 = fmaf(wkB[u], vvB[u].y, aB1);
      aB2 = fmaf(wkB[u], vvB[u].z, aB2); aB3 = fmaf(wkB[u], vvB[u].w, aB3);
    }
  }

  const float scale = scalep[0];
  *(float4*)(&sOut[slA][lane * 4]) = make_float4(scale*aA0, scale*aA1, scale*aA2, scale*aA3);
  *(float4*)(&sOut[slB][lane * 4]) = make_float4(scale*aB0, scale*aB1, scale*aB2, scale*aB3);
  __syncthreads();
  {
    const int t = threadIdx.x;         // b index
    const int g0 = blockIdx.x * 8;
    float4 o1 = make_float4(sOut[0][t], sOut[1][t], sOut[2][t], sOut[3][t]);
    float4 o2 = make_float4(sOut[4][t], sOut[5][t], sOut[6][t], sOut[7][t]);
    *(float4*)(out0 + (size_t)t * G_ROWS + g0)     = o1;
    *(float4*)(out0 + (size_t)t * G_ROWS + g0 + 4) = o2;
  }

  // --- drain zeros (all lanes' stores), then sparse scatters ---
  asm volatile("s_waitcnt vmcnt(0)" ::: "memory");
  if (selA) rowA[idxA] = wA;
  if (selB) rowB[idxB] = wB;
}

extern "C" void kernel_launch(void* const* d_in, const int* in_sizes, int n_in,
                              void* d_out, int out_size, void* d_ws, size_t ws_size,
                              hipStream_t stream)
{
  const float* tg_dec     = (const float*)d_in[0];
  const float* tf_base    = (const float*)d_in[1];
  const float* tf_expr    = (const float*)d_in[2];
  const int*   motif_mask = (const int*)d_in[3];
  const float* scale      = (const float*)d_in[4];

  float* out0 = (float*)d_out;                           // [B, G]
  float* attn = out0 + (size_t)B_DIM * G_ROWS;           // [G, T] — Sim scratch, overwritten in place

  char* ws = (char*)d_ws;
  u16*   Ah    = (u16*)(ws);                             // G_PAD*512 bf16
  u16*   Al    = (u16*)(ws + 20578304);
  u16*   Bh    = (u16*)(ws + 41156608);                  // 1536*512 bf16
  u16*   Bl    = (u16*)(ws + 42729472);
  float* tfT   = (float*)(ws + 44302336);                // [T, B] f32

  prep<<<11200, 256, 0, stream>>>(tg_dec, tf_base, tf_expr, Ah, Al, Bh, Bl, tfT);
  gemm_split<<<NWG, 512, 0, stream>>>(Ah, Al, Bh, Bl, attn);
  topk_combine<<<2500, 256, 0, stream>>>(attn, motif_mask, tg_dec, tf_base, tfT, scale, out0);
}